// Round 5
// baseline (973.878 us; speedup 1.0000x reference)
//
#include <hip/hip_runtime.h>
#include <hip/hip_bf16.h>

#define DIN 128
#define HID 32
#define EPS 1e-5f
#define BINS 16384        // bins per range-pass (LDS: 128KB)
#define CHK 32            // edge chunks (blocks per range)
#define NXCD 8
#define WSC 16384.0f      // 2^14 fixed-point scale for per-chunk w sums
#define WSI 6.103515625e-5f  // 2^-14

typedef unsigned int u32;
typedef unsigned short u16;
typedef unsigned long long u64;

// non-temporal loads: streaming data must NOT allocate in L2, so the L2 can hold
// the scatter write-set (esort segment) / gather table (h2) instead.
__device__ __forceinline__ int ntl_i(const int* p) { return __builtin_nontemporal_load(p); }
__device__ __forceinline__ u32 ntl_u(const u32* p) { return __builtin_nontemporal_load(p); }
__device__ __forceinline__ float ntl_f(const float* p) { return __builtin_nontemporal_load(p); }

// extract bf16 half of a packed u32 (hi=0 -> low 16 bits = even channel) as float
__device__ __forceinline__ float bfx(u32 v, int hi) {
    return __uint_as_float(hi ? (v & 0xffff0000u) : (v << 16));
}

__device__ __forceinline__ u16 f2bf(float f) {
    __hip_bfloat16 h = __float2bfloat16(f);
    return *reinterpret_cast<u16*>(&h);
}

// ---------------- zero BN stats ----------------
__global__ void init_stats(float* __restrict__ stats) {
    if (threadIdx.x < 192) stats[threadIdx.x] = 0.f;
}

// ---------------- counting-sort phase 1: per-(range,chunk) LDS histograms ----------
// bid = c*8 + r so all blocks of range r land on XCD r (round-robin dispatch);
// single u64 LDS atomic per in-range edge: count in hi32, fixed-point w in lo32.
// col/w reads are non-temporal (streaming, re-read cross-XCD -> served by L3).
__global__ __launch_bounds__(1024) void hist_part(
        const int* __restrict__ col, const float* __restrict__ w, int E, int R,
        u32* __restrict__ cpart, u32* __restrict__ wpart) {
    __shared__ u64 cw[BINS];  // 128KB
    int r = blockIdx.x & (NXCD - 1), c = blockIdx.x >> 3;
    if (r >= R) return;
    for (int i = threadIdx.x; i < BINS; i += 1024) cw[i] = 0ull;
    __syncthreads();
    int lo = r * BINS;
    int chunk = (E + CHK - 1) / CHK;
    int e0 = c * chunk;
    int e1 = e0 + chunk; if (e1 > E) e1 = E;
    for (int e = e0 + threadIdx.x; e < e1; e += 1024) {
        int b = ntl_i(&col[e]) - lo;
        if ((u32)b < (u32)BINS) {
            u64 add = (1ull << 32) | (u64)(u32)(ntl_f(&w[e]) * WSC + 0.5f);
            atomicAdd(&cw[b], add);
        }
    }
    __syncthreads();
    size_t base = (size_t)c * ((size_t)R * BINS) + (size_t)r * BINS;
    for (int i = threadIdx.x; i < BINS; i += 1024) {
        u64 v = cw[i];
        cpart[base + i] = (u32)(v >> 32);
        wpart[base + i] = (u32)v;
    }
}

// ---------------- phase 2: per-bin prefix over chunks + counts + dinv ----------------
__global__ void prefix_part(u32* __restrict__ cpart, const u32* __restrict__ wpart,
                            int* __restrict__ rowptr, float* __restrict__ dinv,
                            int N, int R) {
    int rb = blockIdx.x * 256 + threadIdx.x;
    int RB = R * BINS;
    if (rb >= RB) return;
    u32 run = 0;
    u64 wsum = 0;
    for (int c = 0; c < CHK; ++c) {
        size_t idx = (size_t)c * RB + rb;
        u32 cv = cpart[idx];
        cpart[idx] = run;
        run += cv;
        wsum += wpart[idx];
    }
    if (rb < N) {
        rowptr[rb] = (int)run;
        dinv[rb] = rsqrtf(1.0f + (float)wsum * WSI);
    }
}

// ---------------- exclusive scan over rowptr[0..n) ----------------
__global__ void scan_blocks(int* __restrict__ data, int* __restrict__ bsum, int n) {
    __shared__ int s[256];
    int i = blockIdx.x * 256 + threadIdx.x;
    int v = (i < n) ? data[i] : 0;
    s[threadIdx.x] = v;
    __syncthreads();
    for (int off = 1; off < 256; off <<= 1) {
        int t = (threadIdx.x >= off) ? s[threadIdx.x - off] : 0;
        __syncthreads();
        s[threadIdx.x] += t;
        __syncthreads();
    }
    if (i < n) data[i] = s[threadIdx.x] - v;  // exclusive
    if (threadIdx.x == 255) bsum[blockIdx.x] = s[255];
}

__global__ void scan_tops(int* __restrict__ bsum, int nb) {
    __shared__ int s[512];
    int v = (threadIdx.x < nb) ? bsum[threadIdx.x] : 0;
    s[threadIdx.x] = v;
    __syncthreads();
    for (int off = 1; off < 512; off <<= 1) {
        int t = (threadIdx.x >= off) ? s[threadIdx.x - off] : 0;
        __syncthreads();
        s[threadIdx.x] += t;
        __syncthreads();
    }
    if (threadIdx.x < nb) bsum[threadIdx.x] = s[threadIdx.x] - v;  // exclusive
}

__global__ void scan_addback(int* __restrict__ data, const int* __restrict__ bsum,
                             int n, int E) {
    int i = blockIdx.x * 256 + threadIdx.x;
    if (i < n) data[i] += bsum[blockIdx.x];
    if (i == n) data[n] = E;  // sentinel end
}

// ---------------- phase 3: atomic-free scatter into CSR (4-byte packed entries) -----
// bid = c*8 + r: all blocks of range r run on XCD r, so all scattered 4B stores for
// range r's ~1.8MB esort segment land in ONE L2. Edge-stream reads (col/row/w) are
// NON-TEMPORAL so they don't evict the write-set: esort lines fill completely in L2
// and write back once; cross-XCD chunk re-reads are served by the memory-side L3.
// entry = (src << 15) | bf16_bits(norm); norm >= 0 so bf16 sign bit = 0.
__global__ __launch_bounds__(1024) void scatter_sort(
        const int* __restrict__ row, const int* __restrict__ col,
        const float* __restrict__ w, const float* __restrict__ dinv,
        const int* __restrict__ rowptr, const u32* __restrict__ cpart,
        u32* __restrict__ esort, int E, int R) {
    __shared__ u32 cnt[BINS];
    __shared__ u32 basep[BINS];
    int r = blockIdx.x & (NXCD - 1), c = blockIdx.x >> 3;
    if (r >= R) return;
    size_t pb = (size_t)c * ((size_t)R * BINS) + (size_t)r * BINS;
    for (int i = threadIdx.x; i < BINS; i += 1024) {
        cnt[i] = 0;
        basep[i] = cpart[pb + i];
    }
    __syncthreads();
    int lo = r * BINS;
    int chunk = (E + CHK - 1) / CHK;
    int e0 = c * chunk;
    int e1 = e0 + chunk; if (e1 > E) e1 = E;
    for (int e = e0 + threadIdx.x; e < e1; e += 1024) {
        int cc = ntl_i(&col[e]);
        int b = cc - lo;
        if ((u32)b < (u32)BINS) {
            u32 rk = atomicAdd(&cnt[b], 1u);
            int src = ntl_i(&row[e]);
            float nv = dinv[src] * ntl_f(&w[e]) * dinv[cc];
            int pos = rowptr[cc] + (int)basep[b] + (int)rk;
            esort[pos] = ((u32)src << 15) | (u32)f2bf(nv);
        }
    }
}

// ---------------- layer-0 GEMM (x fp32 -> h bf16, split-major halves) ----------------
// LDS-staged: 64 node-rows of x loaded coalesced (float4), then 8 outputs/thread.
__global__ __launch_bounds__(256) void gemm_din(const float* __restrict__ x,
                                                const float* __restrict__ W,
                                                u16* __restrict__ hbf, int n) {
    __shared__ float xl[64][DIN];     // 32KB; xl[nn][k]: 2-way bank alias only (free)
    __shared__ float Wl[DIN * HID];   // 16KB
    int t = threadIdx.x;
    for (int i = t; i < DIN * HID; i += 256) Wl[i] = W[i];
    int nbase = blockIdx.x * 64;
    int nrows = n - nbase; if (nrows > 64) nrows = 64;
    const float4* xv = (const float4*)(x + (size_t)nbase * DIN);
    float4* xlv = (float4*)&xl[0][0];
    int f4cnt = nrows * (DIN / 4);
    for (int i = t; i < f4cnt; i += 256) xlv[i] = xv[i];
    __syncthreads();
    int ch = t & 31, ng = t >> 5;
    for (int nn = ng; nn < nrows; nn += 8) {
        float a0 = 0.f, a1 = 0.f, a2 = 0.f, a3 = 0.f;
#pragma unroll 8
        for (int k = 0; k < DIN; k += 4) {
            a0 += xl[nn][k + 0] * Wl[(k + 0) * HID + ch];
            a1 += xl[nn][k + 1] * Wl[(k + 1) * HID + ch];
            a2 += xl[nn][k + 2] * Wl[(k + 2) * HID + ch];
            a3 += xl[nn][k + 3] * Wl[(k + 3) * HID + ch];
        }
        int node = nbase + nn;
        hbf[(size_t)(ch >> 4) * n * 16 + node * 16 + (ch & 15)] = f2bf((a0 + a1) + (a2 + a3));
    }
}

// ---------------- hidden GEMM, fused BN+ReLU on input (split-major agg in/out) -------
__global__ void gemm_hid_bn(const float* __restrict__ aS, const float* __restrict__ W,
                            const float* __restrict__ stats, const float* __restrict__ g,
                            const float* __restrict__ be, u16* __restrict__ hbf,
                            int n, float invN) {
    __shared__ float Wl[HID * HID];
    __shared__ float sc[HID], sh[HID];
    int t = threadIdx.x;
    for (int i = t; i < HID * HID; i += blockDim.x) Wl[i] = W[i];
    if (t < HID) {
        float mu = stats[t] * invN;
        float var = stats[32 + t] * invN - mu * mu;
        float s = rsqrtf(var + EPS) * g[t];
        sc[t] = s;
        sh[t] = be[t] - mu * s;
    }
    __syncthreads();
    int ch = t & 31;
    int node = blockIdx.x * 8 + (t >> 5);
    if (node >= n) return;
    float acc = 0.f;
#pragma unroll
    for (int k = 0; k < HID; ++k) {
        float av = aS[(size_t)(k >> 4) * n * 16 + node * 16 + (k & 15)];
        float v = fmaxf(av * sc[k] + sh[k], 0.f);
        acc += v * Wl[k * HID + ch];
    }
    hbf[(size_t)(ch >> 4) * n * 16 + node * 16 + (ch & 15)] = f2bf(acc);
}

// ---------------- channel-half CSR gather ----------------
// h2 = this half's packed rows (8 u32/node, 32 B/row, 3.2 MB -> L2-resident).
// esort stream read NON-TEMPORAL so it doesn't evict h2 from L2.
__global__ void gather_half(const u32* __restrict__ h2, const int* __restrict__ rowptr,
                            const u32* __restrict__ esort, const float* __restrict__ dinv,
                            const float* __restrict__ b, float* __restrict__ out,
                            int n, int half) {
    int c = threadIdx.x & 15;
    int node = blockIdx.x * 16 + (threadIdx.x >> 4);
    if (node >= n) return;
    int p = c >> 1, hi = c & 1;
    float dv = dinv[node];
    float acc = dv * dv * bfx(h2[node * 8 + p], hi) + b[half * 16 + c];
    int start = rowptr[node], end = rowptr[node + 1];
    int j = start;
    for (; j + 4 <= end; j += 4) {
        u32 e0 = ntl_u(&esort[j]);
        u32 e1 = ntl_u(&esort[j + 1]);
        u32 e2 = ntl_u(&esort[j + 2]);
        u32 e3 = ntl_u(&esort[j + 3]);
        u32 v0 = h2[(e0 >> 15) * 8 + p];
        u32 v1 = h2[(e1 >> 15) * 8 + p];
        u32 v2 = h2[(e2 >> 15) * 8 + p];
        u32 v3 = h2[(e3 >> 15) * 8 + p];
        acc += __uint_as_float((e0 & 0x7fffu) << 16) * bfx(v0, hi);
        acc += __uint_as_float((e1 & 0x7fffu) << 16) * bfx(v1, hi);
        acc += __uint_as_float((e2 & 0x7fffu) << 16) * bfx(v2, hi);
        acc += __uint_as_float((e3 & 0x7fffu) << 16) * bfx(v3, hi);
    }
    for (; j < end; ++j) {
        u32 ed = ntl_u(&esort[j]);
        acc += __uint_as_float((ed & 0x7fffu) << 16) * bfx(h2[(ed >> 15) * 8 + p], hi);
    }
    out[node * 16 + c] = acc;
}

// ---------------- BN stats reduce (split-major agg) ----------------
__global__ void bn_reduce(const float* __restrict__ aS, float* __restrict__ stats, int n) {
    __shared__ float s1[256], s2[256];
    int ch = threadIdx.x & 31, rg = threadIdx.x >> 5;
    size_t base = (size_t)(ch >> 4) * n * 16 + (ch & 15);
    float a = 0.f, b = 0.f;
    for (int node = blockIdx.x * 8 + rg; node < n; node += gridDim.x * 8) {
        float v = aS[base + node * 16];
        a += v;
        b += v * v;
    }
    s1[threadIdx.x] = a;
    s2[threadIdx.x] = b;
    __syncthreads();
    if (threadIdx.x < 32) {
        float ta = 0.f, tb = 0.f;
#pragma unroll
        for (int j = 0; j < 8; ++j) {
            ta += s1[j * 32 + threadIdx.x];
            tb += s2[j * 32 + threadIdx.x];
        }
        atomicAdd(&stats[threadIdx.x], ta);
        atomicAdd(&stats[32 + threadIdx.x], tb);
    }
}

// ---------------- final merge: split-major agg -> node-major d_out with ReLU --------
__global__ void merge_relu(const float* __restrict__ aS, float* __restrict__ out, int n) {
    int gid = blockIdx.x * blockDim.x + threadIdx.x;
    if (gid >= n * HID) return;
    int node = gid >> 5, ch = gid & 31;
    float v = aS[(size_t)(ch >> 4) * n * 16 + node * 16 + (ch & 15)];
    out[gid] = fmaxf(v, 0.f);
}

extern "C" void kernel_launch(void* const* d_in, const int* in_sizes, int n_in,
                              void* d_out, int out_size, void* d_ws, size_t ws_size,
                              hipStream_t stream) {
    const int N = in_sizes[0] / DIN;
    const int E = in_sizes[2];
    const int R = (N + BINS - 1) / BINS;  // ranges (7 for N=100000)

    const float* x = (const float*)d_in[0];
    const int* ei = (const int*)d_in[1];
    const float* ew = (const float*)d_in[2];
    const int* row = ei;
    const int* col = ei + E;

    const float* Ws[4] = {(const float*)d_in[3], (const float*)d_in[5],
                          (const float*)d_in[7], (const float*)d_in[9]};
    const float* bs[4] = {(const float*)d_in[4], (const float*)d_in[6],
                          (const float*)d_in[8], (const float*)d_in[10]};
    const float* gs[3] = {(const float*)d_in[11], (const float*)d_in[13], (const float*)d_in[15]};
    const float* bes[3] = {(const float*)d_in[12], (const float*)d_in[14], (const float*)d_in[16]};

    // workspace layout, every buffer 256B-aligned (~35 MB total)
    char* wsb = (char*)d_ws;
    size_t off0 = 0;
    auto alloc = [&](size_t bytes) -> void* {
        off0 = (off0 + 255) & ~(size_t)255;
        void* p = wsb + off0;
        off0 += bytes;
        return p;
    };
    const size_t partBytes = (size_t)R * BINS * CHK * 4;  // 14.7 MB at N=100K

    float* dinv = (float*)alloc((size_t)N * 4);
    int* rowptr = (int*)alloc((size_t)(N + 1) * 4);
    // esort (E*4) and hbf (N*HID*2) allocated as ONE region so wpart can alias both:
    // wpart dead after prefix_part; esort first written in scatter_sort, hbf first
    // written by gemm_din which is launched AFTER prefix_part.
    u32* esort = (u32*)alloc((size_t)E * 4 + (size_t)N * HID * 2);
    u16* hbf = (u16*)(esort + E);
    // aggS region sized to also hold cpart: cpart dead after scatter_sort; aggS first
    // written by the layer-0 gathers, which run after scatter_sort.
    size_t aggBytes = (size_t)N * HID * 4;
    float* aggS = (float*)alloc(aggBytes > partBytes ? aggBytes : partBytes);
    float* stats = (float*)alloc(192 * 4);
    int* bsum = (int*)alloc(512 * 4);
    u32* cpart = (u32*)aggS;
    u32* wpart = (u32*)esort;

    const int B = 256;
    const int nodeGrid16 = (N + 15) / 16;
    const int ngrid32 = (N * HID + B - 1) / B;
    const int scanBlocks = (N + 255) / 256;  // 391 <= 512
    const int sortGrid = NXCD * CHK;         // 256 = 1 block/CU; bid = c*8 + r
    const int prefGrid = (R * BINS + 255) / 256;
    const float invN = 1.0f / (float)N;

    // ---- build CSR + norm: atomic-free counting sort, XCD-pinned scatter ----
    init_stats<<<1, 256, 0, stream>>>(stats);
    hist_part<<<sortGrid, 1024, 0, stream>>>(col, ew, E, R, cpart, wpart);
    prefix_part<<<prefGrid, 256, 0, stream>>>(cpart, wpart, rowptr, dinv, N, R);
    gemm_din<<<(N + 63) / 64, 256, 0, stream>>>(x, Ws[0], hbf, N);  // frees wpart alias
    scan_blocks<<<scanBlocks, 256, 0, stream>>>(rowptr, bsum, N);
    scan_tops<<<1, 512, 0, stream>>>(bsum, scanBlocks);
    scan_addback<<<scanBlocks + 1, 256, 0, stream>>>(rowptr, bsum, N, E);
    scatter_sort<<<sortGrid, 1024, 0, stream>>>(row, col, ew, dinv, rowptr, cpart,
                                                esort, E, R);

    // ---- layers ----
    for (int l = 0; l < 4; ++l) {
        if (l > 0)
            gemm_hid_bn<<<(N + 7) / 8, B, 0, stream>>>(aggS, Ws[l], stats + 64 * (l - 1),
                                                       gs[l - 1], bes[l - 1], hbf, N, invN);

        // two channel-half passes; each touches only its 3.2 MB h-half and writes
        // its own contiguous 6.4 MB agg region (no cross-kernel line sharing)
        gather_half<<<nodeGrid16, B, 0, stream>>>((const u32*)hbf, rowptr, esort, dinv,
                                                  bs[l], aggS, N, 0);
        gather_half<<<nodeGrid16, B, 0, stream>>>((const u32*)(hbf + (size_t)N * 16),
                                                  rowptr, esort, dinv, bs[l],
                                                  aggS + (size_t)N * 16, N, 1);

        if (l < 3)
            bn_reduce<<<512, B, 0, stream>>>(aggS, stats + 64 * l, N);
        else
            merge_relu<<<ngrid32, B, 0, stream>>>(aggS, (float*)d_out, N);
    }
}

// Round 7
// 688.907 us; speedup vs baseline: 1.4137x; 1.4137x over previous
//
#include <hip/hip_runtime.h>
#include <hip/hip_bf16.h>

#define DIN 128
#define HID 32
#define EPS 1e-5f
#define BUCK 512          // nodes per bucket
#define BSH 9
#define CHKC 256          // edge chunks
#define WSC 16384.0f      // 2^14 fixed-point scale for w sums
#define WSI 6.103515625e-5f  // 2^-14

typedef unsigned int u32;
typedef unsigned short u16;
typedef unsigned long long u64;

// extract bf16 half of a packed u32 (hi=0 -> low 16 bits = even channel) as float
__device__ __forceinline__ float bfx(u32 v, int hi) {
    return __uint_as_float(hi ? (v & 0xffff0000u) : (v << 16));
}

__device__ __forceinline__ u16 f2bf(float f) {
    __hip_bfloat16 h = __float2bfloat16(f);
    return *reinterpret_cast<u16*>(&h);
}

// ---------------- zero BN stats ----------------
__global__ void init_stats(float* __restrict__ stats) {
    if (threadIdx.x < 192) stats[threadIdx.x] = 0.f;
}

// ---------------- phase A: per-(chunk) LDS bucket histogram ----------------
__global__ __launch_bounds__(1024) void bucket_count(
        const int* __restrict__ col, int E, u32* __restrict__ cpart2, int nbuck) {
    __shared__ u32 cnt[256];
    int c = blockIdx.x;
    for (int i = threadIdx.x; i < nbuck; i += 1024) cnt[i] = 0;
    __syncthreads();
    int chunk = (E + CHKC - 1) / CHKC;
    int e0 = c * chunk, e1 = e0 + chunk;
    if (e1 > E) e1 = E;
    for (int e = e0 + threadIdx.x; e < e1; e += 1024)
        atomicAdd(&cnt[col[e] >> BSH], 1u);
    __syncthreads();
    for (int i = threadIdx.x; i < nbuck; i += 1024)
        cpart2[i * CHKC + c] = cnt[i];
}

// ---------------- exclusive scan (reused for the 50K (bucket,chunk) cells) ---------
__global__ void scan_blocks(int* __restrict__ data, int* __restrict__ bsum, int n) {
    __shared__ int s[256];
    int i = blockIdx.x * 256 + threadIdx.x;
    int v = (i < n) ? data[i] : 0;
    s[threadIdx.x] = v;
    __syncthreads();
    for (int off = 1; off < 256; off <<= 1) {
        int t = (threadIdx.x >= off) ? s[threadIdx.x - off] : 0;
        __syncthreads();
        s[threadIdx.x] += t;
        __syncthreads();
    }
    if (i < n) data[i] = s[threadIdx.x] - v;  // exclusive
    if (threadIdx.x == 255) bsum[blockIdx.x] = s[255];
}

__global__ void scan_tops(int* __restrict__ bsum, int nb) {
    __shared__ int s[512];
    int v = (threadIdx.x < nb) ? bsum[threadIdx.x] : 0;
    s[threadIdx.x] = v;
    __syncthreads();
    for (int off = 1; off < 512; off <<= 1) {
        int t = (threadIdx.x >= off) ? s[threadIdx.x - off] : 0;
        __syncthreads();
        s[threadIdx.x] += t;
        __syncthreads();
    }
    if (threadIdx.x < nb) bsum[threadIdx.x] = s[threadIdx.x] - v;  // exclusive
}

__global__ void scan_addback(int* __restrict__ data, const int* __restrict__ bsum,
                             int n, int E) {
    int i = blockIdx.x * 256 + threadIdx.x;
    if (i < n) data[i] += bsum[blockIdx.x];
    if (i == n) data[n] = E;  // sentinel
}

// ---------------- phase C: bucket-compaction scatter (8B records, split arrays) -----
// Each block keeps ~196 cursor-sequential write runs (~25KB open lines): L1-resident,
// single writer per line -> full-line writebacks, no fabric transaction wall.
// record: loA = (src<<9)|col_in_bucket, hiW = w (f32 bits).
__global__ __launch_bounds__(1024) void bucket_scatter(
        const int* __restrict__ row, const int* __restrict__ col,
        const float* __restrict__ w, const u32* __restrict__ cpart2,
        u32* __restrict__ loA, u32* __restrict__ hiW, int E, int nbuck) {
    __shared__ u32 cur[256];
    int c = blockIdx.x;
    for (int i = threadIdx.x; i < nbuck; i += 1024) cur[i] = cpart2[i * CHKC + c];
    __syncthreads();
    int chunk = (E + CHKC - 1) / CHKC;
    int e0 = c * chunk, e1 = e0 + chunk;
    if (e1 > E) e1 = E;
    for (int e = e0 + threadIdx.x; e < e1; e += 1024) {
        int cc = col[e];
        int b = cc >> BSH;
        u32 pos = atomicAdd(&cur[b], 1u);
        loA[pos] = ((u32)row[e] << BSH) | (u32)(cc & (BUCK - 1));
        hiW[pos] = __float_as_uint(w[e]);
    }
}

// ---------------- phase D: per-bucket hist -> FINAL rowptr + dinv ----------------
// rowptr[g] = bucket record base + in-bucket exclusive prefix (no global scan needed:
// bucket base from the (bucket,chunk) scan IS the global edge offset of the bucket).
__global__ __launch_bounds__(1024) void bucket_hist(
        const u32* __restrict__ loA, const u32* __restrict__ hiW,
        const u32* __restrict__ cpart2, int* __restrict__ rowptr,
        float* __restrict__ dinv, int E, int N, int nbuck) {
    __shared__ u64 cw[BUCK];
    __shared__ int sp[BUCK];
    int b = blockIdx.x, tid = threadIdx.x;
    for (int i = tid; i < BUCK; i += 1024) cw[i] = 0ull;
    __syncthreads();
    int k0 = (int)cpart2[b * CHKC];
    int k1 = (b + 1 < nbuck) ? (int)cpart2[(b + 1) * CHKC] : E;
    for (int k = k0 + tid; k < k1; k += 1024) {
        int i = (int)(loA[k] & (BUCK - 1));
        float wv = __uint_as_float(hiW[k]);
        atomicAdd(&cw[i], (1ull << 32) | (u64)(u32)(wv * WSC + 0.5f));
    }
    __syncthreads();
    if (tid < BUCK) sp[tid] = (int)(cw[tid] >> 32);
    __syncthreads();
    for (int off = 1; off < BUCK; off <<= 1) {
        int t = 0;
        if (tid < BUCK && tid >= off) t = sp[tid - off];
        __syncthreads();
        if (tid < BUCK) sp[tid] += t;
        __syncthreads();
    }
    if (tid < BUCK) {
        int g = (b << BSH) + tid;
        if (g < N) {
            int own = (int)(cw[tid] >> 32);
            rowptr[g] = k0 + sp[tid] - own;  // final (scanned) rowptr
            dinv[g] = rsqrtf(1.0f + (float)(u32)cw[tid] * WSI);  // +1 self loop
        }
    }
    if (b == nbuck - 1 && tid == 0) rowptr[N] = E;
}

// ---------------- phase F: per-bucket rank + norm -> esort ----------------
// Scattered 4B writes confined to this block's PRIVATE ~64KB esort window: lines
// fill completely in one L2 and write back once.
// entry = (src << 15) | bf16_bits(norm); norm >= 0 so bf16 sign bit = 0.
__global__ __launch_bounds__(1024) void bucket_rank(
        const u32* __restrict__ loA, const u32* __restrict__ hiW,
        const u32* __restrict__ cpart2, const int* __restrict__ rowptr,
        const float* __restrict__ dinv, u32* __restrict__ esort,
        int E, int N, int nbuck) {
    __shared__ u32 cnt[BUCK];
    __shared__ float dl[BUCK];
    __shared__ int base[BUCK];
    int b = blockIdx.x, tid = threadIdx.x;
    if (tid < BUCK) {
        int g = (b << BSH) + tid;
        cnt[tid] = 0;
        dl[tid] = (g < N) ? dinv[g] : 0.f;
        base[tid] = (g < N) ? rowptr[g] : 0;
    }
    __syncthreads();
    int k0 = (int)cpart2[b * CHKC];
    int k1 = (b + 1 < nbuck) ? (int)cpart2[(b + 1) * CHKC] : E;
    for (int k = k0 + tid; k < k1; k += 1024) {
        u32 lo = loA[k];
        int i = (int)(lo & (BUCK - 1));
        int src = (int)(lo >> BSH);
        float wv = __uint_as_float(hiW[k]);
        u32 rk = atomicAdd(&cnt[i], 1u);
        float nv = dinv[src] * wv * dl[i];
        esort[base[i] + (int)rk] = ((u32)src << 15) | (u32)f2bf(nv);
    }
}

// ---------------- layer-0 GEMM (x fp32 -> h bf16, split-major halves) ----------------
__global__ __launch_bounds__(256) void gemm_din(const float* __restrict__ x,
                                                const float* __restrict__ W,
                                                u16* __restrict__ hbf, int n) {
    __shared__ float xl[64][DIN];     // 32KB
    __shared__ float Wl[DIN * HID];   // 16KB
    int t = threadIdx.x;
    for (int i = t; i < DIN * HID; i += 256) Wl[i] = W[i];
    int nbase = blockIdx.x * 64;
    int nrows = n - nbase; if (nrows > 64) nrows = 64;
    const float4* xv = (const float4*)(x + (size_t)nbase * DIN);
    float4* xlv = (float4*)&xl[0][0];
    int f4cnt = nrows * (DIN / 4);
    for (int i = t; i < f4cnt; i += 256) xlv[i] = xv[i];
    __syncthreads();
    int ch = t & 31, ng = t >> 5;
    for (int nn = ng; nn < nrows; nn += 8) {
        float a0 = 0.f, a1 = 0.f, a2 = 0.f, a3 = 0.f;
#pragma unroll 8
        for (int k = 0; k < DIN; k += 4) {
            a0 += xl[nn][k + 0] * Wl[(k + 0) * HID + ch];
            a1 += xl[nn][k + 1] * Wl[(k + 1) * HID + ch];
            a2 += xl[nn][k + 2] * Wl[(k + 2) * HID + ch];
            a3 += xl[nn][k + 3] * Wl[(k + 3) * HID + ch];
        }
        int node = nbase + nn;
        hbf[(size_t)(ch >> 4) * n * 16 + node * 16 + (ch & 15)] = f2bf((a0 + a1) + (a2 + a3));
    }
}

// ---------------- hidden GEMM, fused BN+ReLU on input (split-major agg in/out) -------
__global__ void gemm_hid_bn(const float* __restrict__ aS, const float* __restrict__ W,
                            const float* __restrict__ stats, const float* __restrict__ g,
                            const float* __restrict__ be, u16* __restrict__ hbf,
                            int n, float invN) {
    __shared__ float Wl[HID * HID];
    __shared__ float sc[HID], sh[HID];
    int t = threadIdx.x;
    for (int i = t; i < HID * HID; i += blockDim.x) Wl[i] = W[i];
    if (t < HID) {
        float mu = stats[t] * invN;
        float var = stats[32 + t] * invN - mu * mu;
        float s = rsqrtf(var + EPS) * g[t];
        sc[t] = s;
        sh[t] = be[t] - mu * s;
    }
    __syncthreads();
    int ch = t & 31;
    int node = blockIdx.x * 8 + (t >> 5);
    if (node >= n) return;
    float acc = 0.f;
#pragma unroll
    for (int k = 0; k < HID; ++k) {
        float av = aS[(size_t)(k >> 4) * n * 16 + node * 16 + (k & 15)];
        float v = fmaxf(av * sc[k] + sh[k], 0.f);
        acc += v * Wl[k * HID + ch];
    }
    hbf[(size_t)(ch >> 4) * n * 16 + node * 16 + (ch & 15)] = f2bf(acc);
}

// ---------------- channel-half CSR gather ----------------
__global__ void gather_half(const u32* __restrict__ h2, const int* __restrict__ rowptr,
                            const u32* __restrict__ esort, const float* __restrict__ dinv,
                            const float* __restrict__ b, float* __restrict__ out,
                            int n, int half) {
    int c = threadIdx.x & 15;
    int node = blockIdx.x * 16 + (threadIdx.x >> 4);
    if (node >= n) return;
    int p = c >> 1, hi = c & 1;
    float dv = dinv[node];
    float acc = dv * dv * bfx(h2[node * 8 + p], hi) + b[half * 16 + c];
    int start = rowptr[node], end = rowptr[node + 1];
    int j = start;
    for (; j + 4 <= end; j += 4) {
        u32 e0 = esort[j];
        u32 e1 = esort[j + 1];
        u32 e2 = esort[j + 2];
        u32 e3 = esort[j + 3];
        u32 v0 = h2[(e0 >> 15) * 8 + p];
        u32 v1 = h2[(e1 >> 15) * 8 + p];
        u32 v2 = h2[(e2 >> 15) * 8 + p];
        u32 v3 = h2[(e3 >> 15) * 8 + p];
        acc += __uint_as_float((e0 & 0x7fffu) << 16) * bfx(v0, hi);
        acc += __uint_as_float((e1 & 0x7fffu) << 16) * bfx(v1, hi);
        acc += __uint_as_float((e2 & 0x7fffu) << 16) * bfx(v2, hi);
        acc += __uint_as_float((e3 & 0x7fffu) << 16) * bfx(v3, hi);
    }
    for (; j < end; ++j) {
        u32 ed = esort[j];
        acc += __uint_as_float((ed & 0x7fffu) << 16) * bfx(h2[(ed >> 15) * 8 + p], hi);
    }
    out[node * 16 + c] = acc;
}

// ---------------- BN stats reduce (split-major agg) ----------------
__global__ void bn_reduce(const float* __restrict__ aS, float* __restrict__ stats, int n) {
    __shared__ float s1[256], s2[256];
    int ch = threadIdx.x & 31, rg = threadIdx.x >> 5;
    size_t base = (size_t)(ch >> 4) * n * 16 + (ch & 15);
    float a = 0.f, b = 0.f;
    for (int node = blockIdx.x * 8 + rg; node < n; node += gridDim.x * 8) {
        float v = aS[base + node * 16];
        a += v;
        b += v * v;
    }
    s1[threadIdx.x] = a;
    s2[threadIdx.x] = b;
    __syncthreads();
    if (threadIdx.x < 32) {
        float ta = 0.f, tb = 0.f;
#pragma unroll
        for (int j = 0; j < 8; ++j) {
            ta += s1[j * 32 + threadIdx.x];
            tb += s2[j * 32 + threadIdx.x];
        }
        atomicAdd(&stats[threadIdx.x], ta);
        atomicAdd(&stats[32 + threadIdx.x], tb);
    }
}

// ---------------- final merge: split-major agg -> node-major d_out with ReLU --------
__global__ void merge_relu(const float* __restrict__ aS, float* __restrict__ out, int n) {
    int gid = blockIdx.x * blockDim.x + threadIdx.x;
    if (gid >= n * HID) return;
    int node = gid >> 5, ch = gid & 31;
    float v = aS[(size_t)(ch >> 4) * n * 16 + node * 16 + (ch & 15)];
    out[gid] = fmaxf(v, 0.f);
}

extern "C" void kernel_launch(void* const* d_in, const int* in_sizes, int n_in,
                              void* d_out, int out_size, void* d_ws, size_t ws_size,
                              hipStream_t stream) {
    const int N = in_sizes[0] / DIN;
    const int E = in_sizes[2];
    const int nbuck = (N + BUCK - 1) >> BSH;  // 196 for N=100000
    const int nb256 = nbuck * CHKC;           // 50176 (bucket,chunk) cells

    const float* x = (const float*)d_in[0];
    const int* ei = (const int*)d_in[1];
    const float* ew = (const float*)d_in[2];
    const int* row = ei;
    const int* col = ei + E;

    const float* Ws[4] = {(const float*)d_in[3], (const float*)d_in[5],
                          (const float*)d_in[7], (const float*)d_in[9]};
    const float* bs[4] = {(const float*)d_in[4], (const float*)d_in[6],
                          (const float*)d_in[8], (const float*)d_in[10]};
    const float* gs[3] = {(const float*)d_in[11], (const float*)d_in[13], (const float*)d_in[15]};
    const float* bes[3] = {(const float*)d_in[12], (const float*)d_in[14], (const float*)d_in[16]};

    // workspace layout, every buffer 256B-aligned (~33 MB total)
    char* wsb = (char*)d_ws;
    size_t off0 = 0;
    auto alloc = [&](size_t bytes) -> void* {
        off0 = (off0 + 255) & ~(size_t)255;
        void* p = wsb + off0;
        off0 += bytes;
        return p;
    };
    float* dinv = (float*)alloc((size_t)N * 4);
    int* rowptr = (int*)alloc((size_t)(N + 1) * 4);
    u32* esort = (u32*)alloc((size_t)E * 4);
    // combined hbf (6.4M) + aggS (12.8M) region; loA (E*4 = 12.8M) aliases it:
    // loA live phases C..F; hbf first written by gemm_din (after F); aggS first
    // written by layer-0 gathers (after gemm_din).
    char* RR = (char*)alloc((size_t)N * HID * 2 + (size_t)N * HID * 4);
    u16* hbf = (u16*)RR;
    float* aggS = (float*)(RR + (size_t)N * HID * 2);
    u32* loA = (u32*)RR;
    float* stats = (float*)alloc(192 * 4);
    int* bsum = (int*)alloc(512 * 4);
    u32* cpart2 = (u32*)alloc((size_t)(nb256 + 256) * 4);
    // hiW (w f32 per record, E*4 = 12.8MB) lives in d_out: dead before merge_relu.
    u32* hiW = (u32*)d_out;

    const int B = 256;
    const int nodeGrid16 = (N + 15) / 16;
    const int ngrid32 = (N * HID + B - 1) / B;
    const int scanB = (nb256 + 255) / 256;  // 196 <= 512
    const float invN = 1.0f / (float)N;

    // ---- build CSR + norm: two-level bucket counting sort (block-private scatters) --
    init_stats<<<1, 256, 0, stream>>>(stats);
    bucket_count<<<CHKC, 1024, 0, stream>>>(col, E, cpart2, nbuck);
    scan_blocks<<<scanB, 256, 0, stream>>>((int*)cpart2, bsum, nb256);
    scan_tops<<<1, 512, 0, stream>>>(bsum, scanB);
    scan_addback<<<scanB + 1, 256, 0, stream>>>((int*)cpart2, bsum, nb256, E);
    bucket_scatter<<<CHKC, 1024, 0, stream>>>(row, col, ew, cpart2, loA, hiW, E, nbuck);
    bucket_hist<<<nbuck, 1024, 0, stream>>>(loA, hiW, cpart2, rowptr, dinv, E, N, nbuck);
    bucket_rank<<<nbuck, 1024, 0, stream>>>(loA, hiW, cpart2, rowptr, dinv, esort,
                                            E, N, nbuck);
    gemm_din<<<(N + 63) / 64, 256, 0, stream>>>(x, Ws[0], hbf, N);  // frees loA alias

    // ---- layers ----
    for (int l = 0; l < 4; ++l) {
        if (l > 0)
            gemm_hid_bn<<<(N + 7) / 8, B, 0, stream>>>(aggS, Ws[l], stats + 64 * (l - 1),
                                                       gs[l - 1], bes[l - 1], hbf, N, invN);

        // two channel-half passes; each touches only its 3.2 MB h-half and writes
        // its own contiguous 6.4 MB agg region (no cross-kernel line sharing)
        gather_half<<<nodeGrid16, B, 0, stream>>>((const u32*)hbf, rowptr, esort, dinv,
                                                  bs[l], aggS, N, 0);
        gather_half<<<nodeGrid16, B, 0, stream>>>((const u32*)(hbf + (size_t)N * 16),
                                                  rowptr, esort, dinv, bs[l],
                                                  aggS + (size_t)N * 16, N, 1);

        if (l < 3)
            bn_reduce<<<512, B, 0, stream>>>(aggS, stats + 64 * l, N);
        else
            merge_relu<<<ngrid32, B, 0, stream>>>(aggS, (float*)d_out, N);
    }
}

// Round 8
// 615.081 us; speedup vs baseline: 1.5833x; 1.1200x over previous
//
#include <hip/hip_runtime.h>
#include <hip/hip_bf16.h>

#define DIN 128
#define HID 32
#define EPS 1e-5f
#define BUCK 512          // nodes per bucket
#define BSH 9
#define CHKC 256          // edge chunks
#define WSC 16384.0f      // 2^14 fixed-point scale for w sums
#define WSI 6.103515625e-5f  // 2^-14
#define XPAD 132          // x-tile pitch: %4==0 (float4 align), banks (4*nn+k)%32 distinct
#define HPAD 36           // h-tile pitch: %4==0, banks (4*nn+k)%32 distinct

typedef unsigned int u32;
typedef unsigned short u16;
typedef unsigned long long u64;

// extract bf16 half of a packed u32 (hi=0 -> low 16 bits = even channel) as float
__device__ __forceinline__ float bfx(u32 v, int hi) {
    return __uint_as_float(hi ? (v & 0xffff0000u) : (v << 16));
}

__device__ __forceinline__ u16 f2bf(float f) {
    __hip_bfloat16 h = __float2bfloat16(f);
    return *reinterpret_cast<u16*>(&h);
}

// ---------------- zero BN stats ----------------
__global__ void init_stats(float* __restrict__ stats) {
    if (threadIdx.x < 192) stats[threadIdx.x] = 0.f;
}

// ---------------- phase A: per-(chunk) LDS bucket histogram ----------------
__global__ __launch_bounds__(1024) void bucket_count(
        const int* __restrict__ col, int E, u32* __restrict__ cpart2, int nbuck) {
    __shared__ u32 cnt[256];
    int c = blockIdx.x;
    for (int i = threadIdx.x; i < nbuck; i += 1024) cnt[i] = 0;
    __syncthreads();
    int chunk = (E + CHKC - 1) / CHKC;
    int e0 = c * chunk, e1 = e0 + chunk;
    if (e1 > E) e1 = E;
    for (int e = e0 + threadIdx.x; e < e1; e += 1024)
        atomicAdd(&cnt[col[e] >> BSH], 1u);
    __syncthreads();
    for (int i = threadIdx.x; i < nbuck; i += 1024)
        cpart2[i * CHKC + c] = cnt[i];
}

// ---------------- exclusive scan (for the (bucket,chunk) cells) ----------------
__global__ void scan_blocks(int* __restrict__ data, int* __restrict__ bsum, int n) {
    __shared__ int s[256];
    int i = blockIdx.x * 256 + threadIdx.x;
    int v = (i < n) ? data[i] : 0;
    s[threadIdx.x] = v;
    __syncthreads();
    for (int off = 1; off < 256; off <<= 1) {
        int t = (threadIdx.x >= off) ? s[threadIdx.x - off] : 0;
        __syncthreads();
        s[threadIdx.x] += t;
        __syncthreads();
    }
    if (i < n) data[i] = s[threadIdx.x] - v;  // exclusive
    if (threadIdx.x == 255) bsum[blockIdx.x] = s[255];
}

__global__ void scan_tops(int* __restrict__ bsum, int nb) {
    __shared__ int s[512];
    int v = (threadIdx.x < nb) ? bsum[threadIdx.x] : 0;
    s[threadIdx.x] = v;
    __syncthreads();
    for (int off = 1; off < 512; off <<= 1) {
        int t = (threadIdx.x >= off) ? s[threadIdx.x - off] : 0;
        __syncthreads();
        s[threadIdx.x] += t;
        __syncthreads();
    }
    if (threadIdx.x < nb) bsum[threadIdx.x] = s[threadIdx.x] - v;  // exclusive
}

__global__ void scan_addback(int* __restrict__ data, const int* __restrict__ bsum,
                             int n, int E) {
    int i = blockIdx.x * 256 + threadIdx.x;
    if (i < n) data[i] += bsum[blockIdx.x];
    if (i == n) data[n] = E;  // sentinel
}

// ---------------- phase C: bucket-compaction scatter ----------------
// PACKED=1: one 8B store per record into rec8 (u64 = w_bits<<32 | src<<9 | colb):
// halves store transactions and open-line regions vs split 4B arrays.
// PACKED=0 fallback (small ws): lo -> loA, w -> hiW (d_out scratch).
template<int PACKED>
__global__ __launch_bounds__(1024) void bucket_scatter_t(
        const int* __restrict__ row, const int* __restrict__ col,
        const float* __restrict__ w, const u32* __restrict__ cpart2,
        u32* __restrict__ loA, u32* __restrict__ hiW, int E, int nbuck) {
    __shared__ u32 cur[256];
    int c = blockIdx.x;
    for (int i = threadIdx.x; i < nbuck; i += 1024) cur[i] = cpart2[i * CHKC + c];
    __syncthreads();
    int chunk = (E + CHKC - 1) / CHKC;
    int e0 = c * chunk, e1 = e0 + chunk;
    if (e1 > E) e1 = E;
    for (int e = e0 + threadIdx.x; e < e1; e += 1024) {
        int cc = col[e];
        int b = cc >> BSH;
        u32 pos = atomicAdd(&cur[b], 1u);
        u32 lo = ((u32)row[e] << BSH) | (u32)(cc & (BUCK - 1));
        u32 wb = __float_as_uint(w[e]);
        if (PACKED)
            ((u64*)loA)[pos] = ((u64)wb << 32) | (u64)lo;
        else {
            loA[pos] = lo;
            hiW[pos] = wb;
        }
    }
}

// ---------------- phase D: per-bucket hist -> FINAL rowptr + dinv ----------------
template<int PACKED>
__global__ __launch_bounds__(1024) void bucket_hist_t(
        const u32* __restrict__ loA, const u32* __restrict__ hiW,
        const u32* __restrict__ cpart2, int* __restrict__ rowptr,
        float* __restrict__ dinv, int E, int N, int nbuck) {
    __shared__ u64 cw[BUCK];
    __shared__ int sp[BUCK];
    int b = blockIdx.x, tid = threadIdx.x;
    for (int i = tid; i < BUCK; i += 1024) cw[i] = 0ull;
    __syncthreads();
    int k0 = (int)cpart2[b * CHKC];
    int k1 = (b + 1 < nbuck) ? (int)cpart2[(b + 1) * CHKC] : E;
    for (int k = k0 + tid; k < k1; k += 1024) {
        u32 lo, wb;
        if (PACKED) {
            u64 v = ((const u64*)loA)[k];
            lo = (u32)v;
            wb = (u32)(v >> 32);
        } else {
            lo = loA[k];
            wb = hiW[k];
        }
        int i = (int)(lo & (BUCK - 1));
        float wv = __uint_as_float(wb);
        atomicAdd(&cw[i], (1ull << 32) | (u64)(u32)(wv * WSC + 0.5f));
    }
    __syncthreads();
    if (tid < BUCK) sp[tid] = (int)(cw[tid] >> 32);
    __syncthreads();
    for (int off = 1; off < BUCK; off <<= 1) {
        int t = 0;
        if (tid < BUCK && tid >= off) t = sp[tid - off];
        __syncthreads();
        if (tid < BUCK) sp[tid] += t;
        __syncthreads();
    }
    if (tid < BUCK) {
        int g = (b << BSH) + tid;
        if (g < N) {
            int own = (int)(cw[tid] >> 32);
            rowptr[g] = k0 + sp[tid] - own;  // final (scanned) rowptr
            dinv[g] = rsqrtf(1.0f + (float)(u32)cw[tid] * WSI);  // +1 self loop
        }
    }
    if (b == nbuck - 1 && tid == 0) rowptr[N] = E;
}

// ---------------- phase F: per-bucket rank + norm -> esort ----------------
// Scattered 4B writes confined to this block's PRIVATE ~64KB esort window.
// entry = (src << 15) | bf16_bits(norm); norm >= 0 so bf16 sign bit = 0.
template<int PACKED>
__global__ __launch_bounds__(1024) void bucket_rank_t(
        const u32* __restrict__ loA, const u32* __restrict__ hiW,
        const u32* __restrict__ cpart2, const int* __restrict__ rowptr,
        const float* __restrict__ dinv, u32* __restrict__ esort,
        int E, int N, int nbuck) {
    __shared__ u32 cnt[BUCK];
    __shared__ float dl[BUCK];
    __shared__ int base[BUCK];
    int b = blockIdx.x, tid = threadIdx.x;
    if (tid < BUCK) {
        int g = (b << BSH) + tid;
        cnt[tid] = 0;
        dl[tid] = (g < N) ? dinv[g] : 0.f;
        base[tid] = (g < N) ? rowptr[g] : 0;
    }
    __syncthreads();
    int k0 = (int)cpart2[b * CHKC];
    int k1 = (b + 1 < nbuck) ? (int)cpart2[(b + 1) * CHKC] : E;
    for (int k = k0 + tid; k < k1; k += 1024) {
        u32 lo, wb;
        if (PACKED) {
            u64 v = ((const u64*)loA)[k];
            lo = (u32)v;
            wb = (u32)(v >> 32);
        } else {
            lo = loA[k];
            wb = hiW[k];
        }
        int i = (int)(lo & (BUCK - 1));
        int src = (int)(lo >> BSH);
        u32 rk = atomicAdd(&cnt[i], 1u);
        float nv = dinv[src] * __uint_as_float(wb) * dl[i];
        esort[base[i] + (int)rk] = ((u32)src << 15) | (u32)f2bf(nv);
    }
}

// ---------------- layer-0 GEMM (x fp32 -> h bf16, split-major halves) ----------------
// ch-quad threads: per k, ONE ds_read_b128 of the k-major W row quad (8-way lane
// broadcast, banks 0..31 covered -> conflict-free) + one broadcast xl scalar
// (pad 132 -> 8 distinct banks) + 4 FMAs. 6x fewer LDS instrs than scalar version.
__global__ __launch_bounds__(256) void gemm_din(const float* __restrict__ x,
                                                const float* __restrict__ W,
                                                u16* __restrict__ hbf, int n) {
    __shared__ float xl[32][XPAD];   // 16.9KB
    __shared__ float Wl[DIN * HID];  // 16KB, k-major (input layout IS k-major)
    int t = threadIdx.x;
    for (int i = t; i < DIN * HID; i += 256) Wl[i] = W[i];
    int nbase = blockIdx.x * 32;
    int nrows = n - nbase; if (nrows > 32) nrows = 32;
    for (int i = t; i < nrows * 32; i += 256) {  // 32 float4 per row
        int nn = i >> 5, k4 = (i & 31) * 4;
        *(float4*)&xl[nn][k4] = *(const float4*)&x[(size_t)(nbase + nn) * DIN + k4];
    }
    __syncthreads();
    int chq = t & 7, nn = t >> 3;  // 8 ch-quads x 32 nodes
    if (nn >= nrows) return;
    float ax = 0.f, ay = 0.f, az = 0.f, aw = 0.f;
#pragma unroll 8
    for (int k = 0; k < DIN; ++k) {
        float xv = xl[nn][k];
        float4 wv = *(float4*)&Wl[k * HID + chq * 4];
        ax += xv * wv.x; ay += xv * wv.y; az += xv * wv.z; aw += xv * wv.w;
    }
    int ch0 = chq * 4;
    int node = nbase + nn;
    u64 pk = (u64)f2bf(ax) | ((u64)f2bf(ay) << 16) | ((u64)f2bf(az) << 32) |
             ((u64)f2bf(aw) << 48);
    *(u64*)&hbf[(size_t)(ch0 >> 4) * n * 16 + (size_t)node * 16 + (ch0 & 15)] = pk;
}

// ---------------- hidden GEMM, fused BN+ReLU on input (same ch-quad structure) ------
__global__ __launch_bounds__(256) void gemm_hid_bn(
        const float* __restrict__ aS, const float* __restrict__ W,
        const float* __restrict__ stats, const float* __restrict__ g,
        const float* __restrict__ be, u16* __restrict__ hbf, int n, float invN) {
    __shared__ float xl[32][HPAD];   // 4.6KB
    __shared__ float Wl[HID * HID];  // 4KB, k-major
    __shared__ float sc[HID], sh[HID];
    int t = threadIdx.x;
    for (int i = t; i < HID * HID; i += 256) Wl[i] = W[i];
    if (t < HID) {
        float mu = stats[t] * invN;
        float var = stats[32 + t] * invN - mu * mu;
        float s = rsqrtf(var + EPS) * g[t];
        sc[t] = s;
        sh[t] = be[t] - mu * s;
    }
    int nbase = blockIdx.x * 32;
    int nrows = n - nbase; if (nrows > 32) nrows = 32;
    for (int i = t; i < nrows * 8; i += 256) {  // 8 float4 per node (2 halves x 16)
        int nn = i >> 3, q = i & 7;
        int half = q >> 2, kk = (q & 3) * 4;
        *(float4*)&xl[nn][half * 16 + kk] =
            *(const float4*)&aS[(size_t)half * n * 16 + (size_t)(nbase + nn) * 16 + kk];
    }
    __syncthreads();
    int chq = t & 7, nn = t >> 3;
    if (nn >= nrows) return;
    float ax = 0.f, ay = 0.f, az = 0.f, aw = 0.f;
#pragma unroll
    for (int k = 0; k < HID; ++k) {
        float v = fmaxf(xl[nn][k] * sc[k] + sh[k], 0.f);
        float4 wv = *(float4*)&Wl[k * HID + chq * 4];
        ax += v * wv.x; ay += v * wv.y; az += v * wv.z; aw += v * wv.w;
    }
    int ch0 = chq * 4;
    int node = nbase + nn;
    u64 pk = (u64)f2bf(ax) | ((u64)f2bf(ay) << 16) | ((u64)f2bf(az) << 32) |
             ((u64)f2bf(aw) << 48);
    *(u64*)&hbf[(size_t)(ch0 >> 4) * n * 16 + (size_t)node * 16 + (ch0 & 15)] = pk;
}

// ---------------- channel-half CSR gather ----------------
__global__ void gather_half(const u32* __restrict__ h2, const int* __restrict__ rowptr,
                            const u32* __restrict__ esort, const float* __restrict__ dinv,
                            const float* __restrict__ b, float* __restrict__ out,
                            int n, int half) {
    int c = threadIdx.x & 15;
    int node = blockIdx.x * 16 + (threadIdx.x >> 4);
    if (node >= n) return;
    int p = c >> 1, hi = c & 1;
    float dv = dinv[node];
    float acc = dv * dv * bfx(h2[node * 8 + p], hi) + b[half * 16 + c];
    int start = rowptr[node], end = rowptr[node + 1];
    int j = start;
    for (; j + 4 <= end; j += 4) {
        u32 e0 = esort[j];
        u32 e1 = esort[j + 1];
        u32 e2 = esort[j + 2];
        u32 e3 = esort[j + 3];
        u32 v0 = h2[(e0 >> 15) * 8 + p];
        u32 v1 = h2[(e1 >> 15) * 8 + p];
        u32 v2 = h2[(e2 >> 15) * 8 + p];
        u32 v3 = h2[(e3 >> 15) * 8 + p];
        acc += __uint_as_float((e0 & 0x7fffu) << 16) * bfx(v0, hi);
        acc += __uint_as_float((e1 & 0x7fffu) << 16) * bfx(v1, hi);
        acc += __uint_as_float((e2 & 0x7fffu) << 16) * bfx(v2, hi);
        acc += __uint_as_float((e3 & 0x7fffu) << 16) * bfx(v3, hi);
    }
    for (; j < end; ++j) {
        u32 ed = esort[j];
        acc += __uint_as_float((ed & 0x7fffu) << 16) * bfx(h2[(ed >> 15) * 8 + p], hi);
    }
    out[node * 16 + c] = acc;
}

// ---------------- BN stats reduce (split-major agg) ----------------
__global__ void bn_reduce(const float* __restrict__ aS, float* __restrict__ stats, int n) {
    __shared__ float s1[256], s2[256];
    int ch = threadIdx.x & 31, rg = threadIdx.x >> 5;
    size_t base = (size_t)(ch >> 4) * n * 16 + (ch & 15);
    float a = 0.f, b = 0.f;
    for (int node = blockIdx.x * 8 + rg; node < n; node += gridDim.x * 8) {
        float v = aS[base + node * 16];
        a += v;
        b += v * v;
    }
    s1[threadIdx.x] = a;
    s2[threadIdx.x] = b;
    __syncthreads();
    if (threadIdx.x < 32) {
        float ta = 0.f, tb = 0.f;
#pragma unroll
        for (int j = 0; j < 8; ++j) {
            ta += s1[j * 32 + threadIdx.x];
            tb += s2[j * 32 + threadIdx.x];
        }
        atomicAdd(&stats[threadIdx.x], ta);
        atomicAdd(&stats[32 + threadIdx.x], tb);
    }
}

// ---------------- final merge: split-major agg -> node-major d_out with ReLU --------
__global__ void merge_relu(const float* __restrict__ aS, float* __restrict__ out, int n) {
    int gid = blockIdx.x * blockDim.x + threadIdx.x;
    if (gid >= n * HID) return;
    int node = gid >> 5, ch = gid & 31;
    float v = aS[(size_t)(ch >> 4) * n * 16 + node * 16 + (ch & 15)];
    out[gid] = fmaxf(v, 0.f);
}

extern "C" void kernel_launch(void* const* d_in, const int* in_sizes, int n_in,
                              void* d_out, int out_size, void* d_ws, size_t ws_size,
                              hipStream_t stream) {
    const int N = in_sizes[0] / DIN;
    const int E = in_sizes[2];
    const int nbuck = (N + BUCK - 1) >> BSH;  // 196 for N=100000
    const int nb256 = nbuck * CHKC;           // 50176 (bucket,chunk) cells

    const float* x = (const float*)d_in[0];
    const int* ei = (const int*)d_in[1];
    const float* ew = (const float*)d_in[2];
    const int* row = ei;
    const int* col = ei + E;

    const float* Ws[4] = {(const float*)d_in[3], (const float*)d_in[5],
                          (const float*)d_in[7], (const float*)d_in[9]};
    const float* bs[4] = {(const float*)d_in[4], (const float*)d_in[6],
                          (const float*)d_in[8], (const float*)d_in[10]};
    const float* gs[3] = {(const float*)d_in[11], (const float*)d_in[13], (const float*)d_in[15]};
    const float* bes[3] = {(const float*)d_in[12], (const float*)d_in[14], (const float*)d_in[16]};

    // workspace layout, every buffer 256B-aligned
    char* wsb = (char*)d_ws;
    size_t off0 = 0;
    auto alloc = [&](size_t bytes) -> void* {
        off0 = (off0 + 255) & ~(size_t)255;
        void* p = wsb + off0;
        off0 += bytes;
        return p;
    };
    float* dinv = (float*)alloc((size_t)N * 4);
    int* rowptr = (int*)alloc((size_t)(N + 1) * 4);
    u32* esort = (u32*)alloc((size_t)E * 4);
    float* stats = (float*)alloc(192 * 4);
    int* bsum = (int*)alloc(512 * 4);
    u32* cpart2 = (u32*)alloc((size_t)(nb256 + 256) * 4);
    // RR region: hbf (6.4M) + aggS (12.8M); also hosts the edge records, which are
    // dead before gemm_din first writes hbf. PACKED mode needs E*8 here; fallback
    // needs only E*4 (lo) with hiW living in d_out (dead before merge_relu).
    size_t rrMin = (size_t)N * HID * 6;
    size_t rrPacked = (size_t)E * 8 > rrMin ? (size_t)E * 8 : rrMin;
    size_t base256 = (off0 + 255) & ~(size_t)255;
    int packed = (base256 + rrPacked <= ws_size) ? 1 : 0;
    char* RR = (char*)alloc(packed ? rrPacked : rrMin);
    u16* hbf = (u16*)RR;
    float* aggS = (float*)(RR + (size_t)N * HID * 2);
    u32* recLo = (u32*)RR;                 // PACKED: u64 records; else: lo array
    u32* recHi = (u32*)d_out;              // fallback only

    const int B = 256;
    const int nodeGrid16 = (N + 15) / 16;
    const int nodeGrid32 = (N + 31) / 32;
    const int ngrid32 = (N * HID + B - 1) / B;
    const int scanB = (nb256 + 255) / 256;  // 196 <= 512
    const float invN = 1.0f / (float)N;

    // ---- build CSR + norm: two-level bucket counting sort (block-private scatters) --
    init_stats<<<1, 256, 0, stream>>>(stats);
    bucket_count<<<CHKC, 1024, 0, stream>>>(col, E, cpart2, nbuck);
    scan_blocks<<<scanB, 256, 0, stream>>>((int*)cpart2, bsum, nb256);
    scan_tops<<<1, 512, 0, stream>>>(bsum, scanB);
    scan_addback<<<scanB + 1, 256, 0, stream>>>((int*)cpart2, bsum, nb256, E);
    if (packed) {
        bucket_scatter_t<1><<<CHKC, 1024, 0, stream>>>(row, col, ew, cpart2, recLo,
                                                       recHi, E, nbuck);
        bucket_hist_t<1><<<nbuck, 1024, 0, stream>>>(recLo, recHi, cpart2, rowptr,
                                                     dinv, E, N, nbuck);
        bucket_rank_t<1><<<nbuck, 1024, 0, stream>>>(recLo, recHi, cpart2, rowptr,
                                                     dinv, esort, E, N, nbuck);
    } else {
        bucket_scatter_t<0><<<CHKC, 1024, 0, stream>>>(row, col, ew, cpart2, recLo,
                                                       recHi, E, nbuck);
        bucket_hist_t<0><<<nbuck, 1024, 0, stream>>>(recLo, recHi, cpart2, rowptr,
                                                     dinv, E, N, nbuck);
        bucket_rank_t<0><<<nbuck, 1024, 0, stream>>>(recLo, recHi, cpart2, rowptr,
                                                     dinv, esort, E, N, nbuck);
    }
    gemm_din<<<nodeGrid32, 256, 0, stream>>>(x, Ws[0], hbf, N);  // records now dead

    // ---- layers ----
    for (int l = 0; l < 4; ++l) {
        if (l > 0)
            gemm_hid_bn<<<nodeGrid32, 256, 0, stream>>>(aggS, Ws[l], stats + 64 * (l - 1),
                                                        gs[l - 1], bes[l - 1], hbf, N, invN);

        // two channel-half passes; each touches only its 3.2 MB h-half and writes
        // its own contiguous 6.4 MB agg region (no cross-kernel line sharing)
        gather_half<<<nodeGrid16, B, 0, stream>>>((const u32*)hbf, rowptr, esort, dinv,
                                                  bs[l], aggS, N, 0);
        gather_half<<<nodeGrid16, B, 0, stream>>>((const u32*)(hbf + (size_t)N * 16),
                                                  rowptr, esort, dinv, bs[l],
                                                  aggS + (size_t)N * 16, N, 1);

        if (l < 3)
            bn_reduce<<<512, B, 0, stream>>>(aggS, stats + 64 * l, N);
        else
            merge_relu<<<ngrid32, B, 0, stream>>>(aggS, (float*)d_out, N);
    }
}

// Round 9
// 594.044 us; speedup vs baseline: 1.6394x; 1.0354x over previous
//
#include <hip/hip_runtime.h>
#include <hip/hip_bf16.h>

#define DIN 128
#define HID 32
#define EPS 1e-5f
#define BUCK 256          // nodes per bucket
#define BSH 8
#define CHKC 256          // edge chunks
#define SCAP 13000        // staged records per chunk (chunk=12500 for E=3.2M)
#define RCAP 12288        // staged esort entries per bucket (mean 8192, sigma~90)
#define WSC 16384.0f      // 2^14 fixed-point scale for w sums
#define WSI 6.103515625e-5f  // 2^-14

typedef unsigned int u32;
typedef unsigned short u16;
typedef unsigned long long u64;

// extract bf16 half of a packed u32 (hi=0 -> low 16 bits = even channel) as float
__device__ __forceinline__ float bfx(u32 v, int hi) {
    return __uint_as_float(hi ? (v & 0xffff0000u) : (v << 16));
}

__device__ __forceinline__ u16 f2bf(float f) {
    __hip_bfloat16 h = __float2bfloat16(f);
    return *reinterpret_cast<u16*>(&h);
}

// ---------------- zero BN stats ----------------
__global__ void init_stats(float* __restrict__ stats) {
    if (threadIdx.x < 192) stats[threadIdx.x] = 0.f;
}

// ---------------- phase A: per-(chunk) LDS bucket histogram ----------------
__global__ __launch_bounds__(1024) void bucket_count(
        const int* __restrict__ col, int E, u32* __restrict__ cpart2, int nbuck) {
    __shared__ u32 cnt[512];
    int c = blockIdx.x;
    for (int i = threadIdx.x; i < 512; i += 1024) cnt[i] = 0;
    __syncthreads();
    int chunk = (E + CHKC - 1) / CHKC;
    int e0 = c * chunk, e1 = e0 + chunk;
    if (e1 > E) e1 = E;
    for (int e = e0 + threadIdx.x; e < e1; e += 1024)
        atomicAdd(&cnt[col[e] >> BSH], 1u);
    __syncthreads();
    for (int i = threadIdx.x; i < nbuck; i += 1024)
        cpart2[i * CHKC + c] = cnt[i];
}

// ---------------- exclusive scan (for the (bucket,chunk) cells) ----------------
__global__ void scan_blocks(int* __restrict__ data, int* __restrict__ bsum, int n) {
    __shared__ int s[256];
    int i = blockIdx.x * 256 + threadIdx.x;
    int v = (i < n) ? data[i] : 0;
    s[threadIdx.x] = v;
    __syncthreads();
    for (int off = 1; off < 256; off <<= 1) {
        int t = (threadIdx.x >= off) ? s[threadIdx.x - off] : 0;
        __syncthreads();
        s[threadIdx.x] += t;
        __syncthreads();
    }
    if (i < n) data[i] = s[threadIdx.x] - v;  // exclusive
    if (threadIdx.x == 255) bsum[blockIdx.x] = s[255];
}

__global__ void scan_tops(int* __restrict__ bsum, int nb) {
    __shared__ int s[512];
    int v = (threadIdx.x < nb) ? bsum[threadIdx.x] : 0;
    s[threadIdx.x] = v;
    __syncthreads();
    for (int off = 1; off < 512; off <<= 1) {
        int t = (threadIdx.x >= off) ? s[threadIdx.x - off] : 0;
        __syncthreads();
        s[threadIdx.x] += t;
        __syncthreads();
    }
    if (threadIdx.x < nb) bsum[threadIdx.x] = s[threadIdx.x] - v;  // exclusive
}

__global__ void scan_addback(int* __restrict__ data, const int* __restrict__ bsum,
                             int n, int E) {
    int i = blockIdx.x * 256 + threadIdx.x;
    if (i < n) data[i] += bsum[blockIdx.x];
    if (i == n) data[n] = E;  // sentinel
}

// ---------------- phase C: LDS counting-sort scatter (all global writes coalesced) --
// L2 does NOT merge scattered sub-line stores (R8: 8x write amplification even for
// block-private windows). So: sort the chunk's records in LDS (count -> prefix ->
// place via LDS cursors), then copy each bucket-run out contiguously at its cell
// base. record u64 = w_bits<<32 | src<<BSH | col_in_bucket.
__global__ __launch_bounds__(1024) void bucket_scatter(
        const int* __restrict__ row, const int* __restrict__ col,
        const float* __restrict__ w, const u32* __restrict__ cpart2,
        u64* __restrict__ rec8, int E, int nbuck) {
    __shared__ u64 srec[SCAP];                    // 104KB
    __shared__ u32 lcnt[512], lbase[512], lcur[512], cellb[512];
    int c = blockIdx.x, tid = threadIdx.x;
    int chunk = (E + CHKC - 1) / CHKC;
    int e0 = c * chunk, e1 = e0 + chunk;
    if (e1 > E) e1 = E;
    for (int i = tid; i < 512; i += 1024) lcnt[i] = 0;
    __syncthreads();
    if (chunk <= SCAP) {
        // pass 1: count
        for (int e = e0 + tid; e < e1; e += 1024)
            atomicAdd(&lcnt[col[e] >> BSH], 1u);
        __syncthreads();
        // inclusive Hillis-Steele over 512 (barriers block-uniform)
        if (tid < 512) lbase[tid] = lcnt[tid];
        __syncthreads();
        for (int off = 1; off < 512; off <<= 1) {
            u32 t = 0;
            if (tid < 512 && tid >= off) t = lbase[tid - off];
            __syncthreads();
            if (tid < 512) lbase[tid] += t;
            __syncthreads();
        }
        if (tid < 512) {
            lcur[tid] = lbase[tid] - lcnt[tid];  // exclusive base
            cellb[tid] = (tid < nbuck) ? cpart2[tid * CHKC + c] : 0;
        }
        __syncthreads();
        // pass 2: place into LDS
        for (int e = e0 + tid; e < e1; e += 1024) {
            int cc = col[e];
            int b = cc >> BSH;
            u32 p = atomicAdd(&lcur[b], 1u);
            srec[p] = ((u64)__float_as_uint(w[e]) << 32) |
                      ((u64)(u32)row[e] << BSH) | (u64)(u32)(cc & (BUCK - 1));
        }
        __syncthreads();
        // pass 3: coalesced run copy-out (one wave per bucket-run)
        int wv = tid >> 6, lane = tid & 63;
        for (int b = wv; b < nbuck; b += 16) {
            int len = (int)lcnt[b];
            int s = (int)(lbase[b] - lcnt[b]);
            u64* dst = rec8 + cellb[b];
            for (int j = lane; j < len; j += 64) dst[j] = srec[s + j];
        }
    } else {
        // fallback (never for this problem size): direct scattered stores
        if (tid < 512) lcur[tid] = (tid < nbuck) ? cpart2[tid * CHKC + c] : 0;
        __syncthreads();
        for (int e = e0 + tid; e < e1; e += 1024) {
            int cc = col[e];
            int b = cc >> BSH;
            u32 pos = atomicAdd(&lcur[b], 1u);
            rec8[pos] = ((u64)__float_as_uint(w[e]) << 32) |
                        ((u64)(u32)row[e] << BSH) | (u64)(u32)(cc & (BUCK - 1));
        }
    }
}

// ---------------- phase D: per-bucket hist -> FINAL rowptr + dinv ----------------
__global__ __launch_bounds__(1024) void bucket_hist(
        const u64* __restrict__ rec8, const u32* __restrict__ cpart2,
        int* __restrict__ rowptr, float* __restrict__ dinv, int E, int N, int nbuck) {
    __shared__ u64 cw[BUCK];
    __shared__ int sp[BUCK];
    int b = blockIdx.x, tid = threadIdx.x;
    for (int i = tid; i < BUCK; i += 1024) cw[i] = 0ull;
    __syncthreads();
    int k0 = (int)cpart2[b * CHKC];
    int k1 = (b + 1 < nbuck) ? (int)cpart2[(b + 1) * CHKC] : E;
    for (int k = k0 + tid; k < k1; k += 1024) {
        u64 v = rec8[k];
        int i = (int)((u32)v & (BUCK - 1));
        float wv = __uint_as_float((u32)(v >> 32));
        atomicAdd(&cw[i], (1ull << 32) | (u64)(u32)(wv * WSC + 0.5f));
    }
    __syncthreads();
    if (tid < BUCK) sp[tid] = (int)(cw[tid] >> 32);
    __syncthreads();
    for (int off = 1; off < BUCK; off <<= 1) {
        int t = 0;
        if (tid < BUCK && tid >= off) t = sp[tid - off];
        __syncthreads();
        if (tid < BUCK) sp[tid] += t;
        __syncthreads();
    }
    if (tid < BUCK) {
        int g = (b << BSH) + tid;
        if (g < N) {
            int own = (int)(cw[tid] >> 32);
            rowptr[g] = k0 + sp[tid] - own;  // final (scanned) rowptr
            dinv[g] = rsqrtf(1.0f + (float)(u32)cw[tid] * WSI);  // +1 self loop
        }
    }
    if (b == nbuck - 1 && tid == 0) rowptr[N] = E;
}

// ---------------- phase F: per-bucket rank + norm -> LDS-staged esort ----------------
// Scatter into LDS stage (rowptr[g]-k0+rank), then coalesced copy-out: zero global
// write amplification. entry = (src << 15) | bf16_bits(norm).
__global__ __launch_bounds__(1024) void bucket_rank(
        const u64* __restrict__ rec8, const u32* __restrict__ cpart2,
        const int* __restrict__ rowptr, const float* __restrict__ dinv,
        u32* __restrict__ esort, int E, int N, int nbuck) {
    __shared__ u32 stage[RCAP];   // 48KB
    __shared__ u32 cnt[BUCK];
    __shared__ float dl[BUCK];
    __shared__ int baseR[BUCK];
    int b = blockIdx.x, tid = threadIdx.x;
    int k0 = (int)cpart2[b * CHKC];
    int k1 = (b + 1 < nbuck) ? (int)cpart2[(b + 1) * CHKC] : E;
    if (tid < BUCK) {
        int g = (b << BSH) + tid;
        cnt[tid] = 0;
        dl[tid] = (g < N) ? dinv[g] : 0.f;
        baseR[tid] = (g < N) ? rowptr[g] - k0 : 0;
    }
    __syncthreads();
    for (int k = k0 + tid; k < k1; k += 1024) {
        u64 v = rec8[k];
        u32 lo = (u32)v;
        int i = (int)(lo & (BUCK - 1));
        int src = (int)(lo >> BSH);
        u32 rk = atomicAdd(&cnt[i], 1u);
        float nv = dinv[src] * __uint_as_float((u32)(v >> 32)) * dl[i];
        u32 entry = ((u32)src << 15) | (u32)f2bf(nv);
        int off = baseR[i] + (int)rk;
        if (off < RCAP) stage[off] = entry;
        else esort[k0 + off] = entry;  // overflow guard (statistically unreachable)
    }
    __syncthreads();
    int len = k1 - k0;
    int lim = len < RCAP ? len : RCAP;
    for (int j = tid; j < lim; j += 1024) esort[k0 + j] = stage[j];
}

// ---------------- layer-0 GEMM (x fp32 -> h bf16, split-major halves) ----------------
__global__ __launch_bounds__(256) void gemm_din(const float* __restrict__ x,
                                                const float* __restrict__ W,
                                                u16* __restrict__ hbf, int n) {
    __shared__ float xl[32][132];
    __shared__ float Wl[DIN * HID];  // k-major
    int t = threadIdx.x;
    for (int i = t; i < DIN * HID; i += 256) Wl[i] = W[i];
    int nbase = blockIdx.x * 32;
    int nrows = n - nbase; if (nrows > 32) nrows = 32;
    for (int i = t; i < nrows * 32; i += 256) {
        int nn = i >> 5, k4 = (i & 31) * 4;
        *(float4*)&xl[nn][k4] = *(const float4*)&x[(size_t)(nbase + nn) * DIN + k4];
    }
    __syncthreads();
    int chq = t & 7, nn = t >> 3;
    if (nn >= nrows) return;
    float ax = 0.f, ay = 0.f, az = 0.f, aw = 0.f;
#pragma unroll 8
    for (int k = 0; k < DIN; ++k) {
        float xv = xl[nn][k];
        float4 wv = *(float4*)&Wl[k * HID + chq * 4];
        ax += xv * wv.x; ay += xv * wv.y; az += xv * wv.z; aw += xv * wv.w;
    }
    int ch0 = chq * 4;
    int node = nbase + nn;
    u64 pk = (u64)f2bf(ax) | ((u64)f2bf(ay) << 16) | ((u64)f2bf(az) << 32) |
             ((u64)f2bf(aw) << 48);
    *(u64*)&hbf[(size_t)(ch0 >> 4) * n * 16 + (size_t)node * 16 + (ch0 & 15)] = pk;
}

// ---------------- hidden GEMM, fused BN+ReLU on input (split-major agg in/out) -------
__global__ __launch_bounds__(256) void gemm_hid_bn(
        const float* __restrict__ aS, const float* __restrict__ W,
        const float* __restrict__ stats, const float* __restrict__ g,
        const float* __restrict__ be, u16* __restrict__ hbf, int n, float invN) {
    __shared__ float xl[32][36];
    __shared__ float Wl[HID * HID];  // k-major
    __shared__ float sc[HID], sh[HID];
    int t = threadIdx.x;
    for (int i = t; i < HID * HID; i += 256) Wl[i] = W[i];
    if (t < HID) {
        float mu = stats[t] * invN;
        float var = stats[32 + t] * invN - mu * mu;
        float s = rsqrtf(var + EPS) * g[t];
        sc[t] = s;
        sh[t] = be[t] - mu * s;
    }
    int nbase = blockIdx.x * 32;
    int nrows = n - nbase; if (nrows > 32) nrows = 32;
    for (int i = t; i < nrows * 8; i += 256) {
        int nn = i >> 3, q = i & 7;
        int half = q >> 2, kk = (q & 3) * 4;
        *(float4*)&xl[nn][half * 16 + kk] =
            *(const float4*)&aS[(size_t)half * n * 16 + (size_t)(nbase + nn) * 16 + kk];
    }
    __syncthreads();
    int chq = t & 7, nn = t >> 3;
    if (nn >= nrows) return;
    float ax = 0.f, ay = 0.f, az = 0.f, aw = 0.f;
#pragma unroll
    for (int k = 0; k < HID; ++k) {
        float v = fmaxf(xl[nn][k] * sc[k] + sh[k], 0.f);
        float4 wv = *(float4*)&Wl[k * HID + chq * 4];
        ax += v * wv.x; ay += v * wv.y; az += v * wv.z; aw += v * wv.w;
    }
    int ch0 = chq * 4;
    int node = nbase + nn;
    u64 pk = (u64)f2bf(ax) | ((u64)f2bf(ay) << 16) | ((u64)f2bf(az) << 32) |
             ((u64)f2bf(aw) << 48);
    *(u64*)&hbf[(size_t)(ch0 >> 4) * n * 16 + (size_t)node * 16 + (ch0 & 15)] = pk;
}

// ---------------- channel-half CSR gather ----------------
__global__ void gather_half(const u32* __restrict__ h2, const int* __restrict__ rowptr,
                            const u32* __restrict__ esort, const float* __restrict__ dinv,
                            const float* __restrict__ b, float* __restrict__ out,
                            int n, int half) {
    int c = threadIdx.x & 15;
    int node = blockIdx.x * 16 + (threadIdx.x >> 4);
    if (node >= n) return;
    int p = c >> 1, hi = c & 1;
    float dv = dinv[node];
    float acc = dv * dv * bfx(h2[node * 8 + p], hi) + b[half * 16 + c];
    int start = rowptr[node], end = rowptr[node + 1];
    int j = start;
    for (; j + 4 <= end; j += 4) {
        u32 e0 = esort[j];
        u32 e1 = esort[j + 1];
        u32 e2 = esort[j + 2];
        u32 e3 = esort[j + 3];
        u32 v0 = h2[(e0 >> 15) * 8 + p];
        u32 v1 = h2[(e1 >> 15) * 8 + p];
        u32 v2 = h2[(e2 >> 15) * 8 + p];
        u32 v3 = h2[(e3 >> 15) * 8 + p];
        acc += __uint_as_float((e0 & 0x7fffu) << 16) * bfx(v0, hi);
        acc += __uint_as_float((e1 & 0x7fffu) << 16) * bfx(v1, hi);
        acc += __uint_as_float((e2 & 0x7fffu) << 16) * bfx(v2, hi);
        acc += __uint_as_float((e3 & 0x7fffu) << 16) * bfx(v3, hi);
    }
    for (; j < end; ++j) {
        u32 ed = esort[j];
        acc += __uint_as_float((ed & 0x7fffu) << 16) * bfx(h2[(ed >> 15) * 8 + p], hi);
    }
    out[node * 16 + c] = acc;
}

// ---------------- BN stats reduce (split-major agg) ----------------
__global__ void bn_reduce(const float* __restrict__ aS, float* __restrict__ stats, int n) {
    __shared__ float s1[256], s2[256];
    int ch = threadIdx.x & 31, rg = threadIdx.x >> 5;
    size_t base = (size_t)(ch >> 4) * n * 16 + (ch & 15);
    float a = 0.f, b = 0.f;
    for (int node = blockIdx.x * 8 + rg; node < n; node += gridDim.x * 8) {
        float v = aS[base + node * 16];
        a += v;
        b += v * v;
    }
    s1[threadIdx.x] = a;
    s2[threadIdx.x] = b;
    __syncthreads();
    if (threadIdx.x < 32) {
        float ta = 0.f, tb = 0.f;
#pragma unroll
        for (int j = 0; j < 8; ++j) {
            ta += s1[j * 32 + threadIdx.x];
            tb += s2[j * 32 + threadIdx.x];
        }
        atomicAdd(&stats[threadIdx.x], ta);
        atomicAdd(&stats[32 + threadIdx.x], tb);
    }
}

// ---------------- final merge: split-major agg -> node-major d_out with ReLU --------
__global__ void merge_relu(const float* __restrict__ aS, float* __restrict__ out, int n) {
    int gid = blockIdx.x * blockDim.x + threadIdx.x;
    if (gid >= n * HID) return;
    int node = gid >> 5, ch = gid & 31;
    float v = aS[(size_t)(ch >> 4) * n * 16 + node * 16 + (ch & 15)];
    out[gid] = fmaxf(v, 0.f);
}

extern "C" void kernel_launch(void* const* d_in, const int* in_sizes, int n_in,
                              void* d_out, int out_size, void* d_ws, size_t ws_size,
                              hipStream_t stream) {
    const int N = in_sizes[0] / DIN;
    const int E = in_sizes[2];
    const int nbuck = (N + BUCK - 1) >> BSH;  // 391 for N=100000
    const int nb256 = nbuck * CHKC;           // 100096 cells

    const float* x = (const float*)d_in[0];
    const int* ei = (const int*)d_in[1];
    const float* ew = (const float*)d_in[2];
    const int* row = ei;
    const int* col = ei + E;

    const float* Ws[4] = {(const float*)d_in[3], (const float*)d_in[5],
                          (const float*)d_in[7], (const float*)d_in[9]};
    const float* bs[4] = {(const float*)d_in[4], (const float*)d_in[6],
                          (const float*)d_in[8], (const float*)d_in[10]};
    const float* gs[3] = {(const float*)d_in[11], (const float*)d_in[13], (const float*)d_in[15]};
    const float* bes[3] = {(const float*)d_in[12], (const float*)d_in[14], (const float*)d_in[16]};

    // workspace layout, every buffer 256B-aligned (~40 MB total)
    char* wsb = (char*)d_ws;
    size_t off0 = 0;
    auto alloc = [&](size_t bytes) -> void* {
        off0 = (off0 + 255) & ~(size_t)255;
        void* p = wsb + off0;
        off0 += bytes;
        return p;
    };
    float* dinv = (float*)alloc((size_t)N * 4);
    int* rowptr = (int*)alloc((size_t)(N + 1) * 4);
    u32* esort = (u32*)alloc((size_t)E * 4);
    float* stats = (float*)alloc(192 * 4);
    int* bsum = (int*)alloc(512 * 4);
    u32* cpart2 = (u32*)alloc((size_t)(nb256 + 256) * 4);
    // RR region: hbf (6.4M) + aggS (12.8M); rec8 (E*8 = 25.6M) aliases it — rec8
    // dead before gemm_din first writes hbf.
    size_t rrMin = (size_t)N * HID * 6;
    size_t rrBytes = (size_t)E * 8 > rrMin ? (size_t)E * 8 : rrMin;
    char* RR = (char*)alloc(rrBytes);
    u16* hbf = (u16*)RR;
    float* aggS = (float*)(RR + (size_t)N * HID * 2);
    u64* rec8 = (u64*)RR;

    const int B = 256;
    const int nodeGrid16 = (N + 15) / 16;
    const int nodeGrid32 = (N + 31) / 32;
    const int ngrid32 = (N * HID + B - 1) / B;
    const int scanB = (nb256 + 255) / 256;  // 392 <= 512
    const float invN = 1.0f / (float)N;

    // ---- build CSR + norm: LDS counting sort, all global writes coalesced ----
    init_stats<<<1, 256, 0, stream>>>(stats);
    bucket_count<<<CHKC, 1024, 0, stream>>>(col, E, cpart2, nbuck);
    scan_blocks<<<scanB, 256, 0, stream>>>((int*)cpart2, bsum, nb256);
    scan_tops<<<1, 512, 0, stream>>>(bsum, scanB);
    scan_addback<<<scanB + 1, 256, 0, stream>>>((int*)cpart2, bsum, nb256, E);
    bucket_scatter<<<CHKC, 1024, 0, stream>>>(row, col, ew, cpart2, rec8, E, nbuck);
    bucket_hist<<<nbuck, 1024, 0, stream>>>(rec8, cpart2, rowptr, dinv, E, N, nbuck);
    bucket_rank<<<nbuck, 1024, 0, stream>>>(rec8, cpart2, rowptr, dinv, esort, E, N, nbuck);
    gemm_din<<<nodeGrid32, 256, 0, stream>>>(x, Ws[0], hbf, N);  // rec8 now dead

    // ---- layers ----
    for (int l = 0; l < 4; ++l) {
        if (l > 0)
            gemm_hid_bn<<<nodeGrid32, 256, 0, stream>>>(aggS, Ws[l], stats + 64 * (l - 1),
                                                        gs[l - 1], bes[l - 1], hbf, N, invN);

        // two channel-half passes; each touches only its 3.2 MB h-half and writes
        // its own contiguous 6.4 MB agg region (no cross-kernel line sharing)
        gather_half<<<nodeGrid16, B, 0, stream>>>((const u32*)hbf, rowptr, esort, dinv,
                                                  bs[l], aggS, N, 0);
        gather_half<<<nodeGrid16, B, 0, stream>>>((const u32*)(hbf + (size_t)N * 16),
                                                  rowptr, esort, dinv, bs[l],
                                                  aggS + (size_t)N * 16, N, 1);

        if (l < 3)
            bn_reduce<<<512, B, 0, stream>>>(aggS, stats + 64 * l, N);
        else
            merge_relu<<<ngrid32, B, 0, stream>>>(aggS, (float*)d_out, N);
    }
}

// Round 10
// 485.569 us; speedup vs baseline: 2.0056x; 1.2234x over previous
//
#include <hip/hip_runtime.h>
#include <hip/hip_bf16.h>

#define DIN 128
#define HID 32
#define EPS 1e-5f
#define BUCK 256          // nodes per bucket
#define BSH 8
#define CHKC 256          // edge chunks
#define SCAP 13000        // staged records per chunk (chunk=12500 for E=3.2M)
#define RCAP 12288        // staged esort entries per bucket (mean 8192, sigma~90)
#define WSC 16384.0f      // 2^14 fixed-point scale for w sums
#define WSI 6.103515625e-5f  // 2^-14

typedef unsigned int u32;
typedef unsigned short u16;
typedef unsigned long long u64;

// extract bf16 half of a packed u32 (hi=0 -> low 16 bits = even channel) as float
__device__ __forceinline__ float bfx(u32 v, int hi) {
    return __uint_as_float(hi ? (v & 0xffff0000u) : (v << 16));
}

__device__ __forceinline__ u16 f2bf(float f) {
    __hip_bfloat16 h = __float2bfloat16(f);
    return *reinterpret_cast<u16*>(&h);
}

// ---------------- zero BN stats ----------------
__global__ void init_stats(float* __restrict__ stats) {
    if (threadIdx.x < 192) stats[threadIdx.x] = 0.f;
}

// ---------------- phase A: per-(chunk) LDS bucket histogram ----------------
__global__ __launch_bounds__(1024) void bucket_count(
        const int* __restrict__ col, int E, u32* __restrict__ cpart2, int nbuck) {
    __shared__ u32 cnt[512];
    int c = blockIdx.x;
    for (int i = threadIdx.x; i < 512; i += 1024) cnt[i] = 0;
    __syncthreads();
    int chunk = (E + CHKC - 1) / CHKC;
    int e0 = c * chunk, e1 = e0 + chunk;
    if (e1 > E) e1 = E;
    for (int e = e0 + threadIdx.x; e < e1; e += 1024)
        atomicAdd(&cnt[col[e] >> BSH], 1u);
    __syncthreads();
    for (int i = threadIdx.x; i < nbuck; i += 1024)
        cpart2[i * CHKC + c] = cnt[i];
}

// ---------------- exclusive scan (for the (bucket,chunk) cells) ----------------
__global__ void scan_blocks(int* __restrict__ data, int* __restrict__ bsum, int n) {
    __shared__ int s[256];
    int i = blockIdx.x * 256 + threadIdx.x;
    int v = (i < n) ? data[i] : 0;
    s[threadIdx.x] = v;
    __syncthreads();
    for (int off = 1; off < 256; off <<= 1) {
        int t = (threadIdx.x >= off) ? s[threadIdx.x - off] : 0;
        __syncthreads();
        s[threadIdx.x] += t;
        __syncthreads();
    }
    if (i < n) data[i] = s[threadIdx.x] - v;  // exclusive
    if (threadIdx.x == 255) bsum[blockIdx.x] = s[255];
}

__global__ void scan_tops(int* __restrict__ bsum, int nb) {
    __shared__ int s[512];
    int v = (threadIdx.x < nb) ? bsum[threadIdx.x] : 0;
    s[threadIdx.x] = v;
    __syncthreads();
    for (int off = 1; off < 512; off <<= 1) {
        int t = (threadIdx.x >= off) ? s[threadIdx.x - off] : 0;
        __syncthreads();
        s[threadIdx.x] += t;
        __syncthreads();
    }
    if (threadIdx.x < nb) bsum[threadIdx.x] = s[threadIdx.x] - v;  // exclusive
}

__global__ void scan_addback(int* __restrict__ data, const int* __restrict__ bsum,
                             int n, int E) {
    int i = blockIdx.x * 256 + threadIdx.x;
    if (i < n) data[i] += bsum[blockIdx.x];
    if (i == n) data[n] = E;  // sentinel
}

// ---------------- phase C: LDS counting-sort scatter (all global writes coalesced) --
// L2 does NOT merge scattered sub-line stores (R8: 8x write amplification even for
// block-private windows). Sort the chunk's records in LDS, then copy bucket-runs out
// contiguously. record u64 = w_bits<<32 | src<<BSH | col_in_bucket.
__global__ __launch_bounds__(1024) void bucket_scatter(
        const int* __restrict__ row, const int* __restrict__ col,
        const float* __restrict__ w, const u32* __restrict__ cpart2,
        u64* __restrict__ rec8, int E, int nbuck) {
    __shared__ u64 srec[SCAP];                    // 104KB
    __shared__ u32 lcnt[512], lbase[512], lcur[512], cellb[512];
    int c = blockIdx.x, tid = threadIdx.x;
    int chunk = (E + CHKC - 1) / CHKC;
    int e0 = c * chunk, e1 = e0 + chunk;
    if (e1 > E) e1 = E;
    for (int i = tid; i < 512; i += 1024) lcnt[i] = 0;
    __syncthreads();
    if (chunk <= SCAP) {
        for (int e = e0 + tid; e < e1; e += 1024)
            atomicAdd(&lcnt[col[e] >> BSH], 1u);
        __syncthreads();
        if (tid < 512) lbase[tid] = lcnt[tid];
        __syncthreads();
        for (int off = 1; off < 512; off <<= 1) {
            u32 t = 0;
            if (tid < 512 && tid >= off) t = lbase[tid - off];
            __syncthreads();
            if (tid < 512) lbase[tid] += t;
            __syncthreads();
        }
        if (tid < 512) {
            lcur[tid] = lbase[tid] - lcnt[tid];  // exclusive base
            cellb[tid] = (tid < nbuck) ? cpart2[tid * CHKC + c] : 0;
        }
        __syncthreads();
        for (int e = e0 + tid; e < e1; e += 1024) {
            int cc = col[e];
            int b = cc >> BSH;
            u32 p = atomicAdd(&lcur[b], 1u);
            srec[p] = ((u64)__float_as_uint(w[e]) << 32) |
                      ((u64)(u32)row[e] << BSH) | (u64)(u32)(cc & (BUCK - 1));
        }
        __syncthreads();
        int wv = tid >> 6, lane = tid & 63;
        for (int b = wv; b < nbuck; b += 16) {
            int len = (int)lcnt[b];
            int s = (int)(lbase[b] - lcnt[b]);
            u64* dst = rec8 + cellb[b];
            for (int j = lane; j < len; j += 64) dst[j] = srec[s + j];
        }
    } else {
        if (tid < 512) lcur[tid] = (tid < nbuck) ? cpart2[tid * CHKC + c] : 0;
        __syncthreads();
        for (int e = e0 + tid; e < e1; e += 1024) {
            int cc = col[e];
            int b = cc >> BSH;
            u32 pos = atomicAdd(&lcur[b], 1u);
            rec8[pos] = ((u64)__float_as_uint(w[e]) << 32) |
                        ((u64)(u32)row[e] << BSH) | (u64)(u32)(cc & (BUCK - 1));
        }
    }
}

// ---------------- phase D: per-bucket hist -> FINAL rowptr + dinv ----------------
__global__ __launch_bounds__(1024) void bucket_hist(
        const u64* __restrict__ rec8, const u32* __restrict__ cpart2,
        int* __restrict__ rowptr, float* __restrict__ dinv, int E, int N, int nbuck) {
    __shared__ u64 cw[BUCK];
    __shared__ int sp[BUCK];
    int b = blockIdx.x, tid = threadIdx.x;
    for (int i = tid; i < BUCK; i += 1024) cw[i] = 0ull;
    __syncthreads();
    int k0 = (int)cpart2[b * CHKC];
    int k1 = (b + 1 < nbuck) ? (int)cpart2[(b + 1) * CHKC] : E;
    for (int k = k0 + tid; k < k1; k += 1024) {
        u64 v = rec8[k];
        int i = (int)((u32)v & (BUCK - 1));
        float wv = __uint_as_float((u32)(v >> 32));
        atomicAdd(&cw[i], (1ull << 32) | (u64)(u32)(wv * WSC + 0.5f));
    }
    __syncthreads();
    if (tid < BUCK) sp[tid] = (int)(cw[tid] >> 32);
    __syncthreads();
    for (int off = 1; off < BUCK; off <<= 1) {
        int t = 0;
        if (tid < BUCK && tid >= off) t = sp[tid - off];
        __syncthreads();
        if (tid < BUCK) sp[tid] += t;
        __syncthreads();
    }
    if (tid < BUCK) {
        int g = (b << BSH) + tid;
        if (g < N) {
            int own = (int)(cw[tid] >> 32);
            rowptr[g] = k0 + sp[tid] - own;  // final (scanned) rowptr
            dinv[g] = rsqrtf(1.0f + (float)(u32)cw[tid] * WSI);  // +1 self loop
        }
    }
    if (b == nbuck - 1 && tid == 0) rowptr[N] = E;
}

// ---------------- phase F: per-bucket rank + norm -> LDS-staged esort ----------------
__global__ __launch_bounds__(1024) void bucket_rank(
        const u64* __restrict__ rec8, const u32* __restrict__ cpart2,
        const int* __restrict__ rowptr, const float* __restrict__ dinv,
        u32* __restrict__ esort, int E, int N, int nbuck) {
    __shared__ u32 stage[RCAP];   // 48KB
    __shared__ u32 cnt[BUCK];
    __shared__ float dl[BUCK];
    __shared__ int baseR[BUCK];
    int b = blockIdx.x, tid = threadIdx.x;
    int k0 = (int)cpart2[b * CHKC];
    int k1 = (b + 1 < nbuck) ? (int)cpart2[(b + 1) * CHKC] : E;
    if (tid < BUCK) {
        int g = (b << BSH) + tid;
        cnt[tid] = 0;
        dl[tid] = (g < N) ? dinv[g] : 0.f;
        baseR[tid] = (g < N) ? rowptr[g] - k0 : 0;
    }
    __syncthreads();
    for (int k = k0 + tid; k < k1; k += 1024) {
        u64 v = rec8[k];
        u32 lo = (u32)v;
        int i = (int)(lo & (BUCK - 1));
        int src = (int)(lo >> BSH);
        u32 rk = atomicAdd(&cnt[i], 1u);
        float nv = dinv[src] * __uint_as_float((u32)(v >> 32)) * dl[i];
        u32 entry = ((u32)src << 15) | (u32)f2bf(nv);
        int off = baseR[i] + (int)rk;
        if (off < RCAP) stage[off] = entry;
        else esort[k0 + off] = entry;  // overflow guard (statistically unreachable)
    }
    __syncthreads();
    int len = k1 - k0;
    int lim = len < RCAP ? len : RCAP;
    for (int j = tid; j < lim; j += 1024) esort[k0 + j] = stage[j];
}

// ---------------- layer-0 GEMM (x fp32 -> h bf16, NODE-MAJOR: hbf[node*32+ch]) ------
__global__ __launch_bounds__(256) void gemm_din(const float* __restrict__ x,
                                                const float* __restrict__ W,
                                                u16* __restrict__ hbf, int n) {
    __shared__ float xl[32][132];
    __shared__ float Wl[DIN * HID];  // k-major
    int t = threadIdx.x;
    for (int i = t; i < DIN * HID; i += 256) Wl[i] = W[i];
    int nbase = blockIdx.x * 32;
    int nrows = n - nbase; if (nrows > 32) nrows = 32;
    for (int i = t; i < nrows * 32; i += 256) {
        int nn = i >> 5, k4 = (i & 31) * 4;
        *(float4*)&xl[nn][k4] = *(const float4*)&x[(size_t)(nbase + nn) * DIN + k4];
    }
    __syncthreads();
    int chq = t & 7, nn = t >> 3;
    if (nn >= nrows) return;
    float ax = 0.f, ay = 0.f, az = 0.f, aw = 0.f;
#pragma unroll 8
    for (int k = 0; k < DIN; ++k) {
        float xv = xl[nn][k];
        float4 wv = *(float4*)&Wl[k * HID + chq * 4];
        ax += xv * wv.x; ay += xv * wv.y; az += xv * wv.z; aw += xv * wv.w;
    }
    int node = nbase + nn;
    u64 pk = (u64)f2bf(ax) | ((u64)f2bf(ay) << 16) | ((u64)f2bf(az) << 32) |
             ((u64)f2bf(aw) << 48);
    *(u64*)&hbf[(size_t)node * 32 + chq * 4] = pk;
}

// ---------------- hidden GEMM, fused BN+ReLU (node-major agg in, node-major h out) --
__global__ __launch_bounds__(256) void gemm_hid_bn(
        const float* __restrict__ aS, const float* __restrict__ W,
        const float* __restrict__ stats, const float* __restrict__ g,
        const float* __restrict__ be, u16* __restrict__ hbf, int n, float invN) {
    __shared__ float xl[32][36];
    __shared__ float Wl[HID * HID];  // k-major
    __shared__ float sc[HID], sh[HID];
    int t = threadIdx.x;
    for (int i = t; i < HID * HID; i += 256) Wl[i] = W[i];
    if (t < HID) {
        float mu = stats[t] * invN;
        float var = stats[32 + t] * invN - mu * mu;
        float s = rsqrtf(var + EPS) * g[t];
        sc[t] = s;
        sh[t] = be[t] - mu * s;
    }
    int nbase = blockIdx.x * 32;
    int nrows = n - nbase; if (nrows > 32) nrows = 32;
    for (int i = t; i < nrows * 8; i += 256) {
        int nn = i >> 3, q = i & 7;
        *(float4*)&xl[nn][q * 4] =
            *(const float4*)&aS[(size_t)(nbase + nn) * 32 + q * 4];
    }
    __syncthreads();
    int chq = t & 7, nn = t >> 3;
    if (nn >= nrows) return;
    float ax = 0.f, ay = 0.f, az = 0.f, aw = 0.f;
#pragma unroll
    for (int k = 0; k < HID; ++k) {
        float v = fmaxf(xl[nn][k] * sc[k] + sh[k], 0.f);
        float4 wv = *(float4*)&Wl[k * HID + chq * 4];
        ax += v * wv.x; ay += v * wv.y; az += v * wv.z; aw += v * wv.w;
    }
    int node = nbase + nn;
    u64 pk = (u64)f2bf(ax) | ((u64)f2bf(ay) << 16) | ((u64)f2bf(az) << 32) |
             ((u64)f2bf(aw) << 48);
    *(u64*)&hbf[(size_t)node * 32 + chq * 4] = pk;
}

// ---------------- fused full-width CSR gather ----------------
// 8 lanes/node, lane q owns channels 4q..4q+3 via ONE uint2 (8B) load per edge:
// per edge 8 esort + 8 h2 lane-loads (was 64 across the two half-kernels).
// h2 node-major: one 64B line per src node. RELU=1 fuses final ReLU (writes d_out).
template<int RELU>
__global__ __launch_bounds__(256) void gather_t(
        const u32* __restrict__ h2, const int* __restrict__ rowptr,
        const u32* __restrict__ esort, const float* __restrict__ dinv,
        const float* __restrict__ b, float* __restrict__ out, int n) {
    int q = threadIdx.x & 7;
    int node = blockIdx.x * 32 + (threadIdx.x >> 3);
    if (node >= n) return;
    float dv = dinv[node];
    float s = dv * dv;
    uint2 hv = *(const uint2*)&h2[(size_t)node * 16 + q * 2];
    float4 acc;
    acc.x = s * bfx(hv.x, 0) + b[q * 4 + 0];
    acc.y = s * bfx(hv.x, 1) + b[q * 4 + 1];
    acc.z = s * bfx(hv.y, 0) + b[q * 4 + 2];
    acc.w = s * bfx(hv.y, 1) + b[q * 4 + 3];
    int j = rowptr[node], end = rowptr[node + 1];
    for (; j + 4 <= end; j += 4) {
        u32 e0 = esort[j], e1 = esort[j + 1], e2 = esort[j + 2], e3 = esort[j + 3];
        uint2 v0 = *(const uint2*)&h2[(size_t)(e0 >> 15) * 16 + q * 2];
        uint2 v1 = *(const uint2*)&h2[(size_t)(e1 >> 15) * 16 + q * 2];
        uint2 v2 = *(const uint2*)&h2[(size_t)(e2 >> 15) * 16 + q * 2];
        uint2 v3 = *(const uint2*)&h2[(size_t)(e3 >> 15) * 16 + q * 2];
        float n0 = __uint_as_float((e0 & 0x7fffu) << 16);
        float n1 = __uint_as_float((e1 & 0x7fffu) << 16);
        float n2 = __uint_as_float((e2 & 0x7fffu) << 16);
        float n3 = __uint_as_float((e3 & 0x7fffu) << 16);
        acc.x += n0 * bfx(v0.x, 0); acc.y += n0 * bfx(v0.x, 1);
        acc.z += n0 * bfx(v0.y, 0); acc.w += n0 * bfx(v0.y, 1);
        acc.x += n1 * bfx(v1.x, 0); acc.y += n1 * bfx(v1.x, 1);
        acc.z += n1 * bfx(v1.y, 0); acc.w += n1 * bfx(v1.y, 1);
        acc.x += n2 * bfx(v2.x, 0); acc.y += n2 * bfx(v2.x, 1);
        acc.z += n2 * bfx(v2.y, 0); acc.w += n2 * bfx(v2.y, 1);
        acc.x += n3 * bfx(v3.x, 0); acc.y += n3 * bfx(v3.x, 1);
        acc.z += n3 * bfx(v3.y, 0); acc.w += n3 * bfx(v3.y, 1);
    }
    for (; j < end; ++j) {
        u32 ed = esort[j];
        uint2 v = *(const uint2*)&h2[(size_t)(ed >> 15) * 16 + q * 2];
        float nv = __uint_as_float((ed & 0x7fffu) << 16);
        acc.x += nv * bfx(v.x, 0); acc.y += nv * bfx(v.x, 1);
        acc.z += nv * bfx(v.y, 0); acc.w += nv * bfx(v.y, 1);
    }
    if (RELU) {
        acc.x = fmaxf(acc.x, 0.f); acc.y = fmaxf(acc.y, 0.f);
        acc.z = fmaxf(acc.z, 0.f); acc.w = fmaxf(acc.w, 0.f);
    }
    *(float4*)&out[(size_t)node * 32 + q * 4] = acc;
}

// ---------------- BN stats reduce (node-major agg) ----------------
__global__ void bn_reduce(const float* __restrict__ aS, float* __restrict__ stats, int n) {
    __shared__ float s1[256], s2[256];
    int ch = threadIdx.x & 31, rg = threadIdx.x >> 5;
    float a = 0.f, b = 0.f;
    for (int node = blockIdx.x * 8 + rg; node < n; node += gridDim.x * 8) {
        float v = aS[(size_t)node * 32 + ch];
        a += v;
        b += v * v;
    }
    s1[threadIdx.x] = a;
    s2[threadIdx.x] = b;
    __syncthreads();
    if (threadIdx.x < 32) {
        float ta = 0.f, tb = 0.f;
#pragma unroll
        for (int j = 0; j < 8; ++j) {
            ta += s1[j * 32 + threadIdx.x];
            tb += s2[j * 32 + threadIdx.x];
        }
        atomicAdd(&stats[threadIdx.x], ta);
        atomicAdd(&stats[32 + threadIdx.x], tb);
    }
}

extern "C" void kernel_launch(void* const* d_in, const int* in_sizes, int n_in,
                              void* d_out, int out_size, void* d_ws, size_t ws_size,
                              hipStream_t stream) {
    const int N = in_sizes[0] / DIN;
    const int E = in_sizes[2];
    const int nbuck = (N + BUCK - 1) >> BSH;  // 391 for N=100000
    const int nb256 = nbuck * CHKC;           // 100096 cells

    const float* x = (const float*)d_in[0];
    const int* ei = (const int*)d_in[1];
    const float* ew = (const float*)d_in[2];
    const int* row = ei;
    const int* col = ei + E;

    const float* Ws[4] = {(const float*)d_in[3], (const float*)d_in[5],
                          (const float*)d_in[7], (const float*)d_in[9]};
    const float* bs[4] = {(const float*)d_in[4], (const float*)d_in[6],
                          (const float*)d_in[8], (const float*)d_in[10]};
    const float* gs[3] = {(const float*)d_in[11], (const float*)d_in[13], (const float*)d_in[15]};
    const float* bes[3] = {(const float*)d_in[12], (const float*)d_in[14], (const float*)d_in[16]};

    // workspace layout, every buffer 256B-aligned (~40 MB total)
    char* wsb = (char*)d_ws;
    size_t off0 = 0;
    auto alloc = [&](size_t bytes) -> void* {
        off0 = (off0 + 255) & ~(size_t)255;
        void* p = wsb + off0;
        off0 += bytes;
        return p;
    };
    float* dinv = (float*)alloc((size_t)N * 4);
    int* rowptr = (int*)alloc((size_t)(N + 1) * 4);
    u32* esort = (u32*)alloc((size_t)E * 4);
    float* stats = (float*)alloc(192 * 4);
    int* bsum = (int*)alloc(512 * 4);
    u32* cpart2 = (u32*)alloc((size_t)(nb256 + 256) * 4);
    // RR region: hbf (6.4M, node-major) + aggS (12.8M, node-major); rec8 (E*8=25.6M)
    // aliases it — rec8 dead before gemm_din first writes hbf.
    size_t rrMin = (size_t)N * HID * 6;
    size_t rrBytes = (size_t)E * 8 > rrMin ? (size_t)E * 8 : rrMin;
    char* RR = (char*)alloc(rrBytes);
    u16* hbf = (u16*)RR;
    float* aggS = (float*)(RR + (size_t)N * HID * 2);
    u64* rec8 = (u64*)RR;

    const int B = 256;
    const int nodeGrid32 = (N + 31) / 32;
    const int scanB = (nb256 + 255) / 256;  // 392 <= 512
    const float invN = 1.0f / (float)N;

    // ---- build CSR + norm: LDS counting sort, all global writes coalesced ----
    init_stats<<<1, 256, 0, stream>>>(stats);
    bucket_count<<<CHKC, 1024, 0, stream>>>(col, E, cpart2, nbuck);
    scan_blocks<<<scanB, 256, 0, stream>>>((int*)cpart2, bsum, nb256);
    scan_tops<<<1, 512, 0, stream>>>(bsum, scanB);
    scan_addback<<<scanB + 1, 256, 0, stream>>>((int*)cpart2, bsum, nb256, E);
    bucket_scatter<<<CHKC, 1024, 0, stream>>>(row, col, ew, cpart2, rec8, E, nbuck);
    bucket_hist<<<nbuck, 1024, 0, stream>>>(rec8, cpart2, rowptr, dinv, E, N, nbuck);
    bucket_rank<<<nbuck, 1024, 0, stream>>>(rec8, cpart2, rowptr, dinv, esort, E, N, nbuck);
    gemm_din<<<nodeGrid32, 256, 0, stream>>>(x, Ws[0], hbf, N);  // rec8 now dead

    // ---- layers: gemm (l>0) -> fused full-width gather -> bn_reduce ----
    for (int l = 0; l < 4; ++l) {
        if (l > 0)
            gemm_hid_bn<<<nodeGrid32, 256, 0, stream>>>(aggS, Ws[l], stats + 64 * (l - 1),
                                                        gs[l - 1], bes[l - 1], hbf, N, invN);
        if (l < 3) {
            gather_t<0><<<nodeGrid32, B, 0, stream>>>((const u32*)hbf, rowptr, esort,
                                                      dinv, bs[l], aggS, N);
            bn_reduce<<<512, B, 0, stream>>>(aggS, stats + 64 * l, N);
        } else {
            // final layer: gather + ReLU straight to d_out (merge kernel eliminated)
            gather_t<1><<<nodeGrid32, B, 0, stream>>>((const u32*)hbf, rowptr, esort,
                                                      dinv, bs[l], (float*)d_out, N);
        }
    }
}